// Round 3
// baseline (1128.600 us; speedup 1.0000x reference)
//
#include <hip/hip_runtime.h>
#include <hip/hip_bf16.h>

#define B_  2
#define T_  2048
#define D_  1024
#define H_  16
#define DH_ 64
#define HALF_ 128
#define M_  (B_ * T_)   // 4096 rows

typedef __hip_bfloat16 bf16;

// ---- dtype helpers (fp32 primary; bf16 fallback for small workspace) ----
__device__ inline float tof(float x) { return x; }
__device__ inline float tof(bf16 x)  { return __bfloat162float(x); }
__device__ inline void  stv(float* p, float v) { *p = v; }
__device__ inline void  stv(bf16*  p, float v) { *p = __float2bfloat16(v); }
__device__ inline float bfu(unsigned short u) {
    union { unsigned int i; float f; } c; c.i = ((unsigned int)u) << 16; return c.f;
}
__device__ inline float4 ld4(const float* p) { return *(const float4*)p; }
__device__ inline float4 ld4(const bf16* p) {
    ushort4 u = *(const ushort4*)(const void*)p;
    return make_float4(bfu(u.x), bfu(u.y), bfu(u.z), bfu(u.w));
}

// ---------------------------------------------------------------------------
// NT GEMM: C[m,n] = sum_k A[m,k] * W[n,k].  A: MxK (Tin), W: NxK fp32, C (Tout).
// 64x64 tile, BK=16, 256 threads, 4x4 micro-tile, fp32 accumulate.
// ---------------------------------------------------------------------------
template <typename Tin, typename Tout>
__global__ __launch_bounds__(256) void gemm_nt(const Tin* __restrict__ A,
                                               const float* __restrict__ W,
                                               Tout* __restrict__ C,
                                               int M, int N, int K) {
    __shared__ float As[64][17];
    __shared__ float Bs[64][17];
    const int tid = threadIdx.x;
    const int bm = blockIdx.y * 64;
    const int bn = blockIdx.x * 64;
    const int tx = tid & 15;
    const int ty = tid >> 4;
    const int lr = tid >> 2;       // load row 0..63
    const int lc = (tid & 3) * 4;  // load col 0,4,8,12

    float acc[4][4] = {{0.f}};

    for (int k0 = 0; k0 < K; k0 += 16) {
        float4 av = ld4(A + (size_t)(bm + lr) * K + k0 + lc);
        float4 bv = ld4(W + (size_t)(bn + lr) * K + k0 + lc);
        As[lr][lc + 0] = av.x; As[lr][lc + 1] = av.y;
        As[lr][lc + 2] = av.z; As[lr][lc + 3] = av.w;
        Bs[lr][lc + 0] = bv.x; Bs[lr][lc + 1] = bv.y;
        Bs[lr][lc + 2] = bv.z; Bs[lr][lc + 3] = bv.w;
        __syncthreads();
        #pragma unroll
        for (int kk = 0; kk < 16; ++kk) {
            float a[4], b[4];
            #pragma unroll
            for (int i = 0; i < 4; ++i) a[i] = As[ty * 4 + i][kk];
            #pragma unroll
            for (int j = 0; j < 4; ++j) b[j] = Bs[tx * 4 + j][kk];
            #pragma unroll
            for (int i = 0; i < 4; ++i)
                #pragma unroll
                for (int j = 0; j < 4; ++j)
                    acc[i][j] += a[i] * b[j];
        }
        __syncthreads();
    }
    #pragma unroll
    for (int i = 0; i < 4; ++i)
        #pragma unroll
        for (int j = 0; j < 4; ++j)
            stv(&C[(size_t)(bm + ty * 4 + i) * N + bn + tx * 4 + j], acc[i][j]);
}

// ---------------------------------------------------------------------------
// Sliding-window causal attention, one wave per query. j in [max(0,i-128), i].
// q and o may alias (in-place): each wave reads only its own q row (before its
// write) and no other wave ever reads it. All arithmetic finite.
// ---------------------------------------------------------------------------
template <typename S>
__global__ __launch_bounds__(256) void swa_kernel(const S* q,
                                                  const S* __restrict__ k,
                                                  const S* __restrict__ v,
                                                  S* o) {
    __shared__ float sc[4][192];

    const int wave = threadIdx.x >> 6;
    const int lane = threadIdx.x & 63;
    const int qidx = blockIdx.x * 4 + wave;    // 0 .. B*H*T-1
    const int i  = qidx & (T_ - 1);
    const int bh = qidx >> 11;                 // / T_
    const int h  = bh & (H_ - 1);
    const int b  = bh >> 4;

    const size_t rowbase = (size_t)b * T_ * D_ + (size_t)h * DH_;
    const int jlo = (i > HALF_) ? (i - HALF_) : 0;
    const int count = i - jlo + 1;             // 1..129

    // lane holds q dim 'lane', pre-scaled by 1/sqrt(dh)=0.125
    const float qv = tof(q[rowbase + (size_t)i * D_ + lane]) * 0.125f;

    // ---- scores: lanes parallelize over j (3 slots of 64) ----
    float svals[3];
    const S* kbase = k + rowbase;
    #pragma unroll
    for (int t = 0; t < 3; ++t) {
        const int jj = lane + 64 * t;
        const int jc = (jj < count) ? jj : 0;            // clamp keeps lanes active
        const S* kp = kbase + (size_t)(jlo + jc) * D_;
        float acc = 0.f;
        #pragma unroll
        for (int c = 0; c < 16; ++c) {
            float4 kv4 = ld4(kp + c * 4);
            acc += __shfl(qv, c * 4 + 0) * kv4.x;
            acc += __shfl(qv, c * 4 + 1) * kv4.y;
            acc += __shfl(qv, c * 4 + 2) * kv4.z;
            acc += __shfl(qv, c * 4 + 3) * kv4.w;
        }
        svals[t] = (jj < count) ? acc : -1e30f;          // finite sentinel
    }

    // ---- softmax stats (64-lane butterflies) ----
    float m = fmaxf(svals[0], fmaxf(svals[1], svals[2]));
    #pragma unroll
    for (int off = 32; off > 0; off >>= 1) m = fmaxf(m, __shfl_xor(m, off));

    float p[3], lsum = 0.f;
    #pragma unroll
    for (int t = 0; t < 3; ++t) {
        const int jj = lane + 64 * t;
        const float e = __expf(svals[t] - m);            // finite args always
        p[t] = (jj < count) ? e : 0.f;
        lsum += p[t];
    }
    #pragma unroll
    for (int off = 32; off > 0; off >>= 1) lsum += __shfl_xor(lsum, off);
    const float inv_l = 1.f / fmaxf(lsum, 1e-20f);

    sc[wave][lane]       = p[0];
    sc[wave][lane + 64]  = p[1];
    sc[wave][lane + 128] = p[2];
    __syncthreads();

    // ---- output: lane = dim d, coalesced V reads ----
    float oacc = 0.f;
    const S* vbase = v + rowbase + lane;
    for (int jj = 0; jj < count; ++jj) {
        oacc += sc[wave][jj] * tof(vbase[(size_t)(jlo + jj) * D_]);
    }
    stv(&o[rowbase + (size_t)i * D_ + lane], oacc * inv_l);
}

extern "C" void kernel_launch(void* const* d_in, const int* in_sizes, int n_in,
                              void* d_out, int out_size, void* d_ws, size_t ws_size,
                              hipStream_t stream) {
    const float* x  = (const float*)d_in[0];
    const float* Wq = (const float*)d_in[1];
    const float* Wk = (const float*)d_in[2];
    const float* Wv = (const float*)d_in[3];
    const float* Wo = (const float*)d_in[4];
    float* out = (float*)d_out;

    const size_t MD = (size_t)M_ * D_;          // 4,194,304 elements
    dim3 gemm_grid(D_ / 64, M_ / 64);           // (16, 64)
    const int swa_grid = (B_ * H_ * T_) / 4;    // 16384

    if (ws_size >= 2 * MD * sizeof(float)) {
        // fp32 intermediates. K lives in d_out (dead before final GEMM writes it);
        // attention output in-place over Q.
        float* kbuf = out;
        float* vbuf = (float*)d_ws;
        float* qbuf = vbuf + MD;
        gemm_nt<float, float><<<gemm_grid, 256, 0, stream>>>(x, Wk, kbuf, M_, D_, D_);
        gemm_nt<float, float><<<gemm_grid, 256, 0, stream>>>(x, Wv, vbuf, M_, D_, D_);
        gemm_nt<float, float><<<gemm_grid, 256, 0, stream>>>(x, Wq, qbuf, M_, D_, D_);
        swa_kernel<float><<<swa_grid, 256, 0, stream>>>(qbuf, kbuf, vbuf, qbuf);
        gemm_nt<float, float><<<gemm_grid, 256, 0, stream>>>(qbuf, Wo, out, M_, D_, D_);
    } else {
        // bf16 intermediates (16.8 MB ws): error ~0.01 << 0.0603 threshold.
        bf16* kbuf = (bf16*)d_out;
        bf16* vbuf = (bf16*)d_ws;
        bf16* qbuf = vbuf + MD;
        gemm_nt<float, bf16><<<gemm_grid, 256, 0, stream>>>(x, Wk, kbuf, M_, D_, D_);
        gemm_nt<float, bf16><<<gemm_grid, 256, 0, stream>>>(x, Wv, vbuf, M_, D_, D_);
        gemm_nt<float, bf16><<<gemm_grid, 256, 0, stream>>>(x, Wq, qbuf, M_, D_, D_);
        swa_kernel<bf16><<<swa_grid, 256, 0, stream>>>(qbuf, kbuf, vbuf, qbuf);
        gemm_nt<bf16, float><<<gemm_grid, 256, 0, stream>>>(qbuf, Wo, out, M_, D_, D_);
    }
}

// Round 4
// 331.994 us; speedup vs baseline: 3.3995x; 3.3995x over previous
//
#include <hip/hip_runtime.h>
#include <hip/hip_bf16.h>

#define B_  2
#define T_  2048
#define D_  1024
#define H_  16
#define DH_ 64
#define M_  (B_ * T_)   // 4096 rows

typedef short s16x8 __attribute__((ext_vector_type(8)));
typedef float f32x4 __attribute__((ext_vector_type(4)));

__device__ inline float bfu(unsigned short u) {
    union { unsigned int i; float f; } c; c.i = ((unsigned int)u) << 16; return c.f;
}
__device__ inline unsigned short f2bf(float f) {   // round-to-nearest-even
    union { float f; unsigned int i; } c; c.f = f;
    unsigned int r = c.i + 0x7fffu + ((c.i >> 16) & 1u);
    return (unsigned short)(r >> 16);
}
__device__ inline void stv(float* p, float v) { *p = v; }
__device__ inline void stv(unsigned short* p, float v) { *p = f2bf(v); }

// ---------------------------------------------------------------------------
// fp32 -> bf16 conversion of x and the 4 weights into one contiguous ws blob.
// Order: xb (4M elems) | Wq | Wk | Wv | Wo (1M each). 1 group = 4 elems.
// ---------------------------------------------------------------------------
__global__ __launch_bounds__(256) void conv_bf16(const float* __restrict__ x,
                                                 const float* __restrict__ Wq,
                                                 const float* __restrict__ Wk,
                                                 const float* __restrict__ Wv,
                                                 const float* __restrict__ Wo,
                                                 unsigned short* __restrict__ dst) {
    const int g = blockIdx.x * 256 + threadIdx.x;       // 0 .. 2^21-1
    const float* s; size_t o;
    if (g < (1 << 20)) { s = x; o = (size_t)g; }
    else {
        int gg = g - (1 << 20);
        int w = gg >> 18;
        o = (size_t)(gg & ((1 << 18) - 1));
        s = (w == 0) ? Wq : (w == 1) ? Wk : (w == 2) ? Wv : Wo;
    }
    float4 v = ((const float4*)s)[o];
    ushort4 u;
    u.x = f2bf(v.x); u.y = f2bf(v.y); u.z = f2bf(v.z); u.w = f2bf(v.w);
    ((ushort4*)dst)[g] = u;
}

// ---------------------------------------------------------------------------
// MFMA NT GEMM (bf16 in, fp32 acc): C[m,n] = sum_k A[m,k]*Bw[n,k].
// 128x128 tile, BK=32, 256 thr (4 waves in 2x2 of 64x64), 16x16x32 MFMA.
// LDS rows padded to 40 ushorts (stride 20 words, coprime-ish -> 2-way free).
// Verified layouts (m89/m91/m92): A: m=lane&15, k=(lane>>4)*8+j (8 contig);
// B: n=lane&15, same k; C/D: col(n)=lane&15, row(m)=(lane>>4)*4+reg.
// ---------------------------------------------------------------------------
template <typename Tout>
__global__ __launch_bounds__(256) void gemm_nt_mfma(const unsigned short* __restrict__ A,
                                                    const unsigned short* __restrict__ Bw,
                                                    Tout* __restrict__ C,
                                                    int M, int N, int K) {
    __shared__ unsigned short As[128 * 40];
    __shared__ unsigned short Bs[128 * 40];
    const int tid  = threadIdx.x;
    const int lane = tid & 63;
    const int wave = tid >> 6;
    const int wr = wave >> 1, wc = wave & 1;
    const int bm = blockIdx.y * 128, bn = blockIdx.x * 128;
    const int srow = tid >> 1, shalf = tid & 1;     // staging: 2 thr/row, 16 elems each
    const int fr = lane & 15, kg = lane >> 4;

    f32x4 acc[4][4];
    #pragma unroll
    for (int mi = 0; mi < 4; ++mi)
        #pragma unroll
        for (int ni = 0; ni < 4; ++ni)
            #pragma unroll
            for (int r = 0; r < 4; ++r) acc[mi][ni][r] = 0.f;

    for (int k0 = 0; k0 < K; k0 += 32) {
        const uint4* ga = (const uint4*)(A + (size_t)(bm + srow) * K + k0 + shalf * 16);
        uint4 a0 = ga[0], a1 = ga[1];
        const uint4* gb = (const uint4*)(Bw + (size_t)(bn + srow) * K + k0 + shalf * 16);
        uint4 b0 = gb[0], b1 = gb[1];
        __syncthreads();                            // prev-iter LDS reads done
        uint4* la = (uint4*)&As[srow * 40 + shalf * 16]; la[0] = a0; la[1] = a1;
        uint4* lb = (uint4*)&Bs[srow * 40 + shalf * 16]; lb[0] = b0; lb[1] = b1;
        __syncthreads();
        s16x8 af[4], bfv[4];
        #pragma unroll
        for (int mi = 0; mi < 4; ++mi)
            af[mi] = *(const s16x8*)&As[(wr * 64 + mi * 16 + fr) * 40 + kg * 8];
        #pragma unroll
        for (int ni = 0; ni < 4; ++ni)
            bfv[ni] = *(const s16x8*)&Bs[(wc * 64 + ni * 16 + fr) * 40 + kg * 8];
        #pragma unroll
        for (int mi = 0; mi < 4; ++mi)
            #pragma unroll
            for (int ni = 0; ni < 4; ++ni)
                acc[mi][ni] = __builtin_amdgcn_mfma_f32_16x16x32_bf16(af[mi], bfv[ni], acc[mi][ni], 0, 0, 0);
    }

    #pragma unroll
    for (int mi = 0; mi < 4; ++mi)
        #pragma unroll
        for (int ni = 0; ni < 4; ++ni)
            #pragma unroll
            for (int r = 0; r < 4; ++r) {
                int m = bm + wr * 64 + mi * 16 + kg * 4 + r;
                int n = bn + wc * 64 + ni * 16 + fr;
                stv(&C[(size_t)m * N + n], acc[mi][ni][r]);
            }
}

// ---------------------------------------------------------------------------
// K transpose per (b,h): kb[(b*T+t)*D + h*64 + d] -> kt[(b*H+h)*64 + d][t].
// 64x64 LDS tile, pad 66 -> conflict-free, coalesced both sides.
// ---------------------------------------------------------------------------
__global__ __launch_bounds__(256) void transpose_k(const unsigned short* __restrict__ kb,
                                                   unsigned short* __restrict__ kt) {
    __shared__ unsigned short sm[64][66];
    const int tid = threadIdx.x;
    const int t0 = blockIdx.x * 64;
    const int bh = blockIdx.y;
    const int b = bh >> 4, h = bh & 15;
    const unsigned short* src = kb + ((size_t)(b * T_ + t0)) * D_ + h * 64;
    #pragma unroll
    for (int kc = 0; kc < 16; ++kc) {
        int idx = kc * 256 + tid;
        int r = idx >> 6, c = idx & 63;
        sm[r][c] = src[(size_t)r * D_ + c];
    }
    __syncthreads();
    unsigned short* dst = kt + (size_t)bh * 64 * T_ + t0;
    #pragma unroll
    for (int kc = 0; kc < 16; ++kc) {
        int idx = kc * 256 + tid;
        int d = idx >> 6, tt = idx & 63;
        dst[(size_t)d * T_ + tt] = sm[tt][d];
    }
}

// ---------------------------------------------------------------------------
// Sliding-window causal attention, one wave per query, all bf16 in/out.
// K read via kt (coalesced: lane=j along rows of kt[bh][d][:]).
// Window split: 2 slots of 64 cover j = jlo .. i-1, diagonal j=i reduced
// separately from normal-layout kb (1 coalesced load + butterfly).
// In-place o==q safe: wave reads only its own q row before writing it.
// ---------------------------------------------------------------------------
__global__ __launch_bounds__(256) void swa_bf(const unsigned short* qb,
                                              const unsigned short* __restrict__ kbn,
                                              const unsigned short* __restrict__ kt,
                                              const unsigned short* __restrict__ vb,
                                              unsigned short* ob) {
    __shared__ float sc[4][132];

    const int wave = threadIdx.x >> 6;
    const int lane = threadIdx.x & 63;
    const int qidx = blockIdx.x * 4 + wave;
    const int i  = qidx & (T_ - 1);
    const int bh = qidx >> 11;
    const int h  = bh & (H_ - 1);
    const int b  = bh >> 4;

    const size_t rowbase = (size_t)b * T_ * D_ + (size_t)h * DH_;
    const int jlo = (i > 128) ? (i - 128) : 0;
    const int count = i - jlo + 1;          // 1..129
    const int cm1 = count - 1;              // slots cover jj in [0, cm1)

    const float qv = bfu(qb[rowbase + (size_t)i * D_ + lane]) * 0.125f;

    // diagonal score (j = i): per-lane product from normal-layout K + butterfly
    float sd = qv * bfu(kbn[rowbase + (size_t)i * D_ + lane]);
    #pragma unroll
    for (int off = 32; off > 0; off >>= 1) sd += __shfl_xor(sd, off);

    // slot scores, coalesced kt reads
    const unsigned short* ktb = kt + (size_t)bh * 64 * T_;
    const int c0 = jlo + ((lane      < cm1) ? lane      : 0);
    const int c1 = jlo + ((lane + 64 < cm1) ? lane + 64 : 0);
    float s0 = 0.f, s1 = 0.f;
    #pragma unroll
    for (int d = 0; d < 64; ++d) {
        const float qd = __shfl(qv, d);
        const unsigned short* kr = ktb + (size_t)d * T_;
        s0 += qd * bfu(kr[c0]);
        s1 += qd * bfu(kr[c1]);
    }
    const float s0v = (lane      < cm1) ? s0 : -1e30f;
    const float s1v = (lane + 64 < cm1) ? s1 : -1e30f;

    float mx = fmaxf(fmaxf(s0v, s1v), sd);
    #pragma unroll
    for (int off = 32; off > 0; off >>= 1) mx = fmaxf(mx, __shfl_xor(mx, off));

    const float p0 = (lane      < cm1) ? __expf(s0 - mx) : 0.f;
    const float p1 = (lane + 64 < cm1) ? __expf(s1 - mx) : 0.f;
    const float pd = __expf(sd - mx);
    float ls = p0 + p1;
    #pragma unroll
    for (int off = 32; off > 0; off >>= 1) ls += __shfl_xor(ls, off);
    ls += pd;                               // diag added once (same on all lanes)
    const float inv_l = 1.f / ls;

    sc[wave][lane]      = p0;
    sc[wave][lane + 64] = p1;
    sc[wave][cm1]       = pd;               // after slot stores; same value all lanes
    __syncthreads();

    float oa = 0.f;
    const unsigned short* v2 = vb + rowbase + lane;
    for (int jj = 0; jj <= cm1; ++jj)
        oa += sc[wave][jj] * bfu(v2[(size_t)(jlo + jj) * D_]);
    ob[rowbase + (size_t)i * D_ + lane] = f2bf(oa * inv_l);
}

extern "C" void kernel_launch(void* const* d_in, const int* in_sizes, int n_in,
                              void* d_out, int out_size, void* d_ws, size_t ws_size,
                              hipStream_t stream) {
    const float* x  = (const float*)d_in[0];
    const float* Wq = (const float*)d_in[1];
    const float* Wk = (const float*)d_in[2];
    const float* Wv = (const float*)d_in[3];
    const float* Wo = (const float*)d_in[4];

    const size_t MD = (size_t)M_ * D_;      // 4,194,304
    const size_t WN = (size_t)D_ * D_;      // 1,048,576

    // ws (bf16): xb | Wqb | Wkb | Wvb | Wob | qb | vb   = 16M elems = 32 MB
    unsigned short* wsb = (unsigned short*)d_ws;
    unsigned short* xb  = wsb;
    unsigned short* Wqb = xb + MD;
    unsigned short* Wkb = Wqb + WN;
    unsigned short* Wvb = Wkb + WN;
    unsigned short* Wob = Wvb + WN;
    unsigned short* qb  = Wob + WN;
    unsigned short* vb  = qb + MD;
    // d_out (16 MB) doubles as kb | kt until the final GEMM overwrites it
    unsigned short* kb = (unsigned short*)d_out;
    unsigned short* kt = kb + MD;

    conv_bf16<<<8192, 256, 0, stream>>>(x, Wq, Wk, Wv, Wo, wsb);

    dim3 gg(D_ / 128, M_ / 128);            // (8, 32)
    gemm_nt_mfma<unsigned short><<<gg, 256, 0, stream>>>(xb, Wkb, kb, M_, D_, D_);
    transpose_k<<<dim3(T_ / 64, B_ * H_), 256, 0, stream>>>(kb, kt);
    gemm_nt_mfma<unsigned short><<<gg, 256, 0, stream>>>(xb, Wvb, vb, M_, D_, D_);
    gemm_nt_mfma<unsigned short><<<gg, 256, 0, stream>>>(xb, Wqb, qb, M_, D_, D_);

    swa_bf<<<(B_ * H_ * T_) / 4, 256, 0, stream>>>(qb, kb, kt, vb, qb);

    gemm_nt_mfma<float><<<gg, 256, 0, stream>>>(qb, Wob, (float*)d_out, M_, D_, D_);
}

// Round 5
// 228.373 us; speedup vs baseline: 4.9419x; 1.4537x over previous
//
#include <hip/hip_runtime.h>
#include <hip/hip_bf16.h>

#define B_  2
#define T_  2048
#define D_  1024
#define H_  16
#define DH_ 64
#define M_  (B_ * T_)   // 4096 rows

typedef short s16x8 __attribute__((ext_vector_type(8)));
typedef float f32x4 __attribute__((ext_vector_type(4)));

__device__ inline float bfu(unsigned short u) {
    union { unsigned int i; float f; } c; c.i = ((unsigned int)u) << 16; return c.f;
}
__device__ inline unsigned short f2bf(float f) {   // round-to-nearest-even
    union { float f; unsigned int i; } c; c.f = f;
    unsigned int r = c.i + 0x7fffu + ((c.i >> 16) & 1u);
    return (unsigned short)(r >> 16);
}
__device__ inline void stv(float* p, float v) { *p = v; }
__device__ inline void stv(unsigned short* p, float v) { *p = f2bf(v); }

// ---------------------------------------------------------------------------
// fp32 -> bf16 conversion of x and the 4 weights into one contiguous ws blob.
// ---------------------------------------------------------------------------
__global__ __launch_bounds__(256) void conv_bf16(const float* __restrict__ x,
                                                 const float* __restrict__ Wq,
                                                 const float* __restrict__ Wk,
                                                 const float* __restrict__ Wv,
                                                 const float* __restrict__ Wo,
                                                 unsigned short* __restrict__ dst) {
    const int g = blockIdx.x * 256 + threadIdx.x;       // 0 .. 2^21-1
    const float* s; size_t o;
    if (g < (1 << 20)) { s = x; o = (size_t)g; }
    else {
        int gg = g - (1 << 20);
        int w = gg >> 18;
        o = (size_t)(gg & ((1 << 18) - 1));
        s = (w == 0) ? Wq : (w == 1) ? Wk : (w == 2) ? Wv : Wo;
    }
    float4 v = ((const float4*)s)[o];
    ushort4 u;
    u.x = f2bf(v.x); u.y = f2bf(v.y); u.z = f2bf(v.z); u.w = f2bf(v.w);
    ((ushort4*)dst)[g] = u;
}

// ---------------------------------------------------------------------------
// MFMA NT GEMM (bf16 in, fp32 acc): C[m,n] = sum_k A[m,k]*Bw[n,k].
// 128x128 tile, BK=32, 256 thr, 16x16x32 MFMA. (validated round 4)
// ---------------------------------------------------------------------------
template <typename Tout>
__global__ __launch_bounds__(256) void gemm_nt_mfma(const unsigned short* __restrict__ A,
                                                    const unsigned short* __restrict__ Bw,
                                                    Tout* __restrict__ C,
                                                    int M, int N, int K) {
    __shared__ unsigned short As[128 * 40];
    __shared__ unsigned short Bs[128 * 40];
    const int tid  = threadIdx.x;
    const int lane = tid & 63;
    const int wave = tid >> 6;
    const int wr = wave >> 1, wc = wave & 1;
    const int bm = blockIdx.y * 128, bn = blockIdx.x * 128;
    const int srow = tid >> 1, shalf = tid & 1;
    const int fr = lane & 15, kg = lane >> 4;

    f32x4 acc[4][4];
    #pragma unroll
    for (int mi = 0; mi < 4; ++mi)
        #pragma unroll
        for (int ni = 0; ni < 4; ++ni)
            #pragma unroll
            for (int r = 0; r < 4; ++r) acc[mi][ni][r] = 0.f;

    for (int k0 = 0; k0 < K; k0 += 32) {
        const uint4* ga = (const uint4*)(A + (size_t)(bm + srow) * K + k0 + shalf * 16);
        uint4 a0 = ga[0], a1 = ga[1];
        const uint4* gb = (const uint4*)(Bw + (size_t)(bn + srow) * K + k0 + shalf * 16);
        uint4 b0 = gb[0], b1 = gb[1];
        __syncthreads();
        uint4* la = (uint4*)&As[srow * 40 + shalf * 16]; la[0] = a0; la[1] = a1;
        uint4* lb = (uint4*)&Bs[srow * 40 + shalf * 16]; lb[0] = b0; lb[1] = b1;
        __syncthreads();
        s16x8 af[4], bfv[4];
        #pragma unroll
        for (int mi = 0; mi < 4; ++mi)
            af[mi] = *(const s16x8*)&As[(wr * 64 + mi * 16 + fr) * 40 + kg * 8];
        #pragma unroll
        for (int ni = 0; ni < 4; ++ni)
            bfv[ni] = *(const s16x8*)&Bs[(wc * 64 + ni * 16 + fr) * 40 + kg * 8];
        #pragma unroll
        for (int mi = 0; mi < 4; ++mi)
            #pragma unroll
            for (int ni = 0; ni < 4; ++ni)
                acc[mi][ni] = __builtin_amdgcn_mfma_f32_16x16x32_bf16(af[mi], bfv[ni], acc[mi][ni], 0, 0, 0);
    }

    #pragma unroll
    for (int mi = 0; mi < 4; ++mi)
        #pragma unroll
        for (int ni = 0; ni < 4; ++ni)
            #pragma unroll
            for (int r = 0; r < 4; ++r) {
                int m = bm + wr * 64 + mi * 16 + kg * 4 + r;
                int n = bn + wc * 64 + ni * 16 + fr;
                stv(&C[(size_t)m * N + n], acc[mi][ni][r]);
            }
}

// ---------------------------------------------------------------------------
// Transpose per (b,h): src[(b*T+t)*D + h*64 + d] -> dst[(b*H+h)*64 + d][t].
// ---------------------------------------------------------------------------
__global__ __launch_bounds__(256) void transpose_bh(const unsigned short* __restrict__ src0,
                                                    unsigned short* __restrict__ dst) {
    __shared__ unsigned short sm[64][66];
    const int tid = threadIdx.x;
    const int t0 = blockIdx.x * 64;
    const int bh = blockIdx.y;
    const int b = bh >> 4, h = bh & 15;
    const unsigned short* src = src0 + ((size_t)(b * T_ + t0)) * D_ + h * 64;
    #pragma unroll
    for (int kc = 0; kc < 16; ++kc) {
        int idx = kc * 256 + tid;
        int r = idx >> 6, c = idx & 63;
        sm[r][c] = src[(size_t)r * D_ + c];
    }
    __syncthreads();
    unsigned short* d2 = dst + (size_t)bh * 64 * T_ + t0;
    #pragma unroll
    for (int kc = 0; kc < 16; ++kc) {
        int idx = kc * 256 + tid;
        int d = idx >> 6, tt = idx & 63;
        d2[(size_t)d * T_ + tt] = sm[tt][d];
    }
}

// ---------------------------------------------------------------------------
// MFMA sliding-window attention. One wave per 16-query tile (same b,h).
// Keys span exactly [klo, klo+143], klo = max(0, i0-128): 9 S-tiles of 16.
// QK^T: A=Q rows (global), B=K rows (global, K-contiguous -> no transpose).
// Softmax in C/D layout (row = (lane>>4)*4+r, col = lane&15), group shfl.
// P -> LDS bf16 (stride 168: 16B-aligned b128 reads), PV from vt (d-major).
// o==q in-place safe: wave reads only its own 16 q rows before writing them.
// ---------------------------------------------------------------------------
__global__ __launch_bounds__(256) void swa_mfma(const unsigned short* qb,
                                                const unsigned short* __restrict__ kb,
                                                const unsigned short* __restrict__ vt,
                                                unsigned short* ob) {
    __shared__ unsigned short Pl[4][16 * 168];
    const int wave = threadIdx.x >> 6;
    const int lane = threadIdx.x & 63;
    const int qt = blockIdx.x * 4 + wave;          // Q-tile id, 0..4095
    const int i0 = (qt & (T_ / 16 - 1)) * 16;
    const int bh = qt >> 7;
    const int h = bh & (H_ - 1), b = bh >> 4;
    const int g = lane >> 4, l15 = lane & 15;

    const size_t rowbase = (size_t)b * T_ * D_ + (size_t)h * DH_;
    const int klo = (i0 > 128) ? (i0 - 128) : 0;

    unsigned short* Pw = Pl[wave];
    // zero-pad P cols 144..159 (read by the last PV k-tile)
    {
        int row = lane >> 2, col = 144 + (lane & 3) * 4;
        *(uint2*)&Pw[row * 168 + col] = make_uint2(0u, 0u);
    }

    // Q fragments (A): m = l15 -> query i0+l15, k = g*8 + e
    const unsigned short* qrow = qb + rowbase + (size_t)(i0 + l15) * D_ + g * 8;
    const s16x8 aq0 = *(const s16x8*)(qrow);
    const s16x8 aq1 = *(const s16x8*)(qrow + 32);

    // ---- S = Q K^T over 9 key tiles ----
    f32x4 sacc[9];
    #pragma unroll
    for (int t = 0; t < 9; ++t)
        #pragma unroll
        for (int r = 0; r < 4; ++r) sacc[t][r] = 0.f;

    const unsigned short* kbase = kb + rowbase;
    #pragma unroll
    for (int t = 0; t < 9; ++t) {
        const unsigned short* krow = kbase + (size_t)(klo + t * 16 + l15) * D_ + g * 8;
        s16x8 b0 = *(const s16x8*)(krow);
        s16x8 b1 = *(const s16x8*)(krow + 32);
        sacc[t] = __builtin_amdgcn_mfma_f32_16x16x32_bf16(aq0, b0, sacc[t], 0, 0, 0);
        sacc[t] = __builtin_amdgcn_mfma_f32_16x16x32_bf16(aq1, b1, sacc[t], 0, 0, 0);
    }

    // ---- mask + scale + softmax (rows g*4+r, cols l15 per tile) ----
    float mrow[4] = {-1e30f, -1e30f, -1e30f, -1e30f};
    #pragma unroll
    for (int t = 0; t < 9; ++t)
        #pragma unroll
        for (int r = 0; r < 4; ++r) {
            const int j  = klo + t * 16 + l15;
            const int iq = i0 + g * 4 + r;
            const bool valid = (j <= iq) && (j + 128 >= iq);
            const float s = valid ? sacc[t][r] * 0.125f : -1e30f;
            sacc[t][r] = s;
            mrow[r] = fmaxf(mrow[r], s);
        }
    #pragma unroll
    for (int r = 0; r < 4; ++r)
        #pragma unroll
        for (int off = 1; off < 16; off <<= 1)
            mrow[r] = fmaxf(mrow[r], __shfl_xor(mrow[r], off));

    float lrow[4] = {0.f, 0.f, 0.f, 0.f};
    #pragma unroll
    for (int t = 0; t < 9; ++t)
        #pragma unroll
        for (int r = 0; r < 4; ++r) {
            const float p = __expf(sacc[t][r] - mrow[r]);   // masked -> exp(-huge)=0
            sacc[t][r] = p;
            lrow[r] += p;
        }
    #pragma unroll
    for (int r = 0; r < 4; ++r) {
        #pragma unroll
        for (int off = 1; off < 16; off <<= 1)
            lrow[r] += __shfl_xor(lrow[r], off);
    }
    float invl[4];
    #pragma unroll
    for (int r = 0; r < 4; ++r) invl[r] = 1.f / lrow[r];

    // ---- P (bf16) -> LDS in C-layout ----
    #pragma unroll
    for (int t = 0; t < 9; ++t)
        #pragma unroll
        for (int r = 0; r < 4; ++r)
            Pw[(g * 4 + r) * 168 + t * 16 + l15] = f2bf(sacc[t][r]);

    // ---- O = P V : A = P from LDS, B = V^T rows (d-major, key-contiguous) ----
    f32x4 oacc[4];
    #pragma unroll
    for (int nt = 0; nt < 4; ++nt)
        #pragma unroll
        for (int r = 0; r < 4; ++r) oacc[nt][r] = 0.f;

    const unsigned short* vtb = vt + (size_t)bh * 64 * T_;
    #pragma unroll
    for (int kt = 0; kt < 5; ++kt) {
        const s16x8 ap = *(const s16x8*)&Pw[l15 * 168 + kt * 32 + g * 8];
        #pragma unroll
        for (int nt = 0; nt < 4; ++nt) {
            const unsigned short* vrow = vtb + (size_t)(nt * 16 + l15) * T_ + klo + kt * 32 + g * 8;
            s16x8 bv = *(const s16x8*)vrow;
            oacc[nt] = __builtin_amdgcn_mfma_f32_16x16x32_bf16(ap, bv, oacc[nt], 0, 0, 0);
        }
    }

    // ---- epilogue: rows g*4+r match invl mapping ----
    #pragma unroll
    for (int nt = 0; nt < 4; ++nt)
        #pragma unroll
        for (int r = 0; r < 4; ++r) {
            const float val = oacc[nt][r] * invl[r];
            ob[rowbase + (size_t)(i0 + g * 4 + r) * D_ + nt * 16 + l15] = f2bf(val);
        }
}

extern "C" void kernel_launch(void* const* d_in, const int* in_sizes, int n_in,
                              void* d_out, int out_size, void* d_ws, size_t ws_size,
                              hipStream_t stream) {
    const float* x  = (const float*)d_in[0];
    const float* Wq = (const float*)d_in[1];
    const float* Wk = (const float*)d_in[2];
    const float* Wv = (const float*)d_in[3];
    const float* Wo = (const float*)d_in[4];

    const size_t MD = (size_t)M_ * D_;      // 4,194,304
    const size_t WN = (size_t)D_ * D_;      // 1,048,576

    // ws (bf16): xb | Wqb | Wkb | Wvb | Wob | qb | vb = 16M elems = 32 MB
    unsigned short* wsb = (unsigned short*)d_ws;
    unsigned short* xb  = wsb;
    unsigned short* Wqb = xb + MD;
    unsigned short* Wkb = Wqb + WN;
    unsigned short* Wvb = Wkb + WN;
    unsigned short* Wob = Wvb + WN;
    unsigned short* qb  = Wob + WN;
    unsigned short* vb  = qb + MD;
    // d_out doubles as vt | kb until the final GEMM overwrites it.
    // vt FIRST: its benign 15-elem tail over-read lands in kb, not past d_out.
    unsigned short* vt = (unsigned short*)d_out;
    unsigned short* kb = vt + MD;

    conv_bf16<<<8192, 256, 0, stream>>>(x, Wq, Wk, Wv, Wo, wsb);

    dim3 gg(D_ / 128, M_ / 128);            // (8, 32)
    gemm_nt_mfma<unsigned short><<<gg, 256, 0, stream>>>(xb, Wvb, vb, M_, D_, D_);
    transpose_bh<<<dim3(T_ / 64, B_ * H_), 256, 0, stream>>>(vb, vt);
    gemm_nt_mfma<unsigned short><<<gg, 256, 0, stream>>>(xb, Wkb, kb, M_, D_, D_);
    gemm_nt_mfma<unsigned short><<<gg, 256, 0, stream>>>(xb, Wqb, qb, M_, D_, D_);

    swa_mfma<<<(B_ * H_ * T_ / 16) / 4, 256, 0, stream>>>(qb, kb, vt, qb);

    gemm_nt_mfma<float><<<gg, 256, 0, stream>>>(qb, Wob, (float*)d_out, M_, D_, D_);
}

// Round 6
// 174.118 us; speedup vs baseline: 6.4818x; 1.3116x over previous
//
#include <hip/hip_runtime.h>
#include <hip/hip_bf16.h>

#define B_  2
#define T_  2048
#define D_  1024
#define H_  16
#define DH_ 64
#define M_  (B_ * T_)   // 4096 rows

typedef short s16x8 __attribute__((ext_vector_type(8)));
typedef float f32x4 __attribute__((ext_vector_type(4)));

__device__ inline float bfu(unsigned short u) {
    union { unsigned int i; float f; } c; c.i = ((unsigned int)u) << 16; return c.f;
}
__device__ inline unsigned short f2bf(float f) {   // round-to-nearest-even
    union { float f; unsigned int i; } c; c.f = f;
    unsigned int r = c.i + 0x7fffu + ((c.i >> 16) & 1u);
    return (unsigned short)(r >> 16);
}
__device__ inline void stv(float* p, float v) { *p = v; }
__device__ inline void stv(unsigned short* p, float v) { *p = f2bf(v); }

// async global->LDS, 16B per lane; lds base must be wave-uniform (HW adds lane*16)
__device__ inline void gload_lds16(const unsigned short* g, unsigned short* l) {
    __builtin_amdgcn_global_load_lds(
        (const __attribute__((address_space(1))) void*)g,
        (__attribute__((address_space(3))) void*)l, 16, 0, 0);
}

// ---------------------------------------------------------------------------
// fp32 -> bf16 conversion of x and the 4 weights into one contiguous ws blob.
// ---------------------------------------------------------------------------
__global__ __launch_bounds__(256) void conv_bf16(const float* __restrict__ x,
                                                 const float* __restrict__ Wq,
                                                 const float* __restrict__ Wk,
                                                 const float* __restrict__ Wv,
                                                 const float* __restrict__ Wo,
                                                 unsigned short* __restrict__ dst) {
    const int g = blockIdx.x * 256 + threadIdx.x;       // 0 .. 2^21-1
    const float* s; size_t o;
    if (g < (1 << 20)) { s = x; o = (size_t)g; }
    else {
        int gg = g - (1 << 20);
        int w = gg >> 18;
        o = (size_t)(gg & ((1 << 18) - 1));
        s = (w == 0) ? Wq : (w == 1) ? Wk : (w == 2) ? Wv : Wo;
    }
    float4 v = ((const float4*)s)[o];
    ushort4 u;
    u.x = f2bf(v.x); u.y = f2bf(v.y); u.z = f2bf(v.z); u.w = f2bf(v.w);
    ((ushort4*)dst)[g] = u;
}

// ---------------------------------------------------------------------------
// m97-style MFMA NT GEMM (bf16 in, fp32 acc): C[m,n] = sum_k A[m,k]*Bw[n,k].
// 128x128 tile, BK=32, 256 thr (2x2 waves of 64x64), 16x16x32 MFMA.
// Staging: global_load_lds width=16, unpadded LDS rows (32 ushorts = 64 B);
// per instruction one wave fills 16 rows (lane -> row lane>>2, chunk lane&3).
// Output row stride fixed at 1024 (= D_); buffer selected per 128-wide n-tile
// (bn/1024) so one launch computes x@[Wq|Wk|Wv]^T into q/k/v.
// ---------------------------------------------------------------------------
template <typename Tout>
__global__ __launch_bounds__(256) void gemm_m97(const unsigned short* __restrict__ A,
                                                const unsigned short* __restrict__ Bw,
                                                Tout* __restrict__ C0,
                                                Tout* __restrict__ C1,
                                                Tout* __restrict__ C2,
                                                int K) {
    __shared__ unsigned short As[128 * 32];
    __shared__ unsigned short Bs[128 * 32];
    const int tid  = threadIdx.x;
    const int lane = tid & 63;
    const int wave = tid >> 6;
    const int wr = wave >> 1, wc = wave & 1;
    const int bm = blockIdx.y * 128, bn = blockIdx.x * 128;
    const int fr = lane & 15, kg = lane >> 4;
    const int lrow = lane >> 2;          // staging row within 16-row window
    const int lcol = (lane & 3) * 8;     // staging 16B chunk (ushort offset)

    f32x4 acc[4][4];
    #pragma unroll
    for (int mi = 0; mi < 4; ++mi)
        #pragma unroll
        for (int ni = 0; ni < 4; ++ni)
            #pragma unroll
            for (int r = 0; r < 4; ++r) acc[mi][ni][r] = 0.f;

    const unsigned short* ga = A  + (size_t)(bm + wave * 16 + lrow) * K + lcol;
    const unsigned short* gb = Bw + (size_t)(bn + wave * 16 + lrow) * K + lcol;
    unsigned short* la = &As[(wave * 16) * 32];   // wave-uniform
    unsigned short* lb = &Bs[(wave * 16) * 32];

    for (int k0 = 0; k0 < K; k0 += 32) {
        __syncthreads();                          // prev-iter LDS reads done
        gload_lds16(ga + k0,                 la);
        gload_lds16(ga + k0 + (size_t)64 * K, la + 64 * 32);
        gload_lds16(gb + k0,                 lb);
        gload_lds16(gb + k0 + (size_t)64 * K, lb + 64 * 32);
        __syncthreads();                          // vmcnt drained: tile visible
        s16x8 af[4], bfv[4];
        #pragma unroll
        for (int mi = 0; mi < 4; ++mi)
            af[mi] = *(const s16x8*)&As[(wr * 64 + mi * 16 + fr) * 32 + kg * 8];
        #pragma unroll
        for (int ni = 0; ni < 4; ++ni)
            bfv[ni] = *(const s16x8*)&Bs[(wc * 64 + ni * 16 + fr) * 32 + kg * 8];
        #pragma unroll
        for (int mi = 0; mi < 4; ++mi)
            #pragma unroll
            for (int ni = 0; ni < 4; ++ni)
                acc[mi][ni] = __builtin_amdgcn_mfma_f32_16x16x32_bf16(af[mi], bfv[ni], acc[mi][ni], 0, 0, 0);
    }

    Tout* C = (bn < 1024) ? C0 : (bn < 2048) ? C1 : C2;
    const int nb = bn & 1023;
    #pragma unroll
    for (int mi = 0; mi < 4; ++mi)
        #pragma unroll
        for (int ni = 0; ni < 4; ++ni)
            #pragma unroll
            for (int r = 0; r < 4; ++r) {
                int m = bm + wr * 64 + mi * 16 + kg * 4 + r;
                int n = nb + wc * 64 + ni * 16 + fr;
                stv(&C[(size_t)m * 1024 + n], acc[mi][ni][r]);
            }
}

// ---------------------------------------------------------------------------
// Transpose per (b,h): src[(b*T+t)*D + h*64 + d] -> dst[(b*H+h)*64 + d][t].
// ---------------------------------------------------------------------------
__global__ __launch_bounds__(256) void transpose_bh(const unsigned short* __restrict__ src0,
                                                    unsigned short* __restrict__ dst) {
    __shared__ unsigned short sm[64][66];
    const int tid = threadIdx.x;
    const int t0 = blockIdx.x * 64;
    const int bh = blockIdx.y;
    const int b = bh >> 4, h = bh & 15;
    const unsigned short* src = src0 + ((size_t)(b * T_ + t0)) * D_ + h * 64;
    #pragma unroll
    for (int kc = 0; kc < 16; ++kc) {
        int idx = kc * 256 + tid;
        int r = idx >> 6, c = idx & 63;
        sm[r][c] = src[(size_t)r * D_ + c];
    }
    __syncthreads();
    unsigned short* d2 = dst + (size_t)bh * 64 * T_ + t0;
    #pragma unroll
    for (int kc = 0; kc < 16; ++kc) {
        int idx = kc * 256 + tid;
        int d = idx >> 6, tt = idx & 63;
        d2[(size_t)d * T_ + tt] = sm[tt][d];
    }
}

// ---------------------------------------------------------------------------
// MFMA sliding-window attention (validated round 5). One wave per 16 queries.
// ---------------------------------------------------------------------------
__global__ __launch_bounds__(256) void swa_mfma(const unsigned short* qb,
                                                const unsigned short* __restrict__ kb,
                                                const unsigned short* __restrict__ vt,
                                                unsigned short* ob) {
    __shared__ unsigned short Pl[4][16 * 168];
    const int wave = threadIdx.x >> 6;
    const int lane = threadIdx.x & 63;
    const int qt = blockIdx.x * 4 + wave;          // Q-tile id, 0..4095
    const int i0 = (qt & (T_ / 16 - 1)) * 16;
    const int bh = qt >> 7;
    const int h = bh & (H_ - 1), b = bh >> 4;
    const int g = lane >> 4, l15 = lane & 15;

    const size_t rowbase = (size_t)b * T_ * D_ + (size_t)h * DH_;
    const int klo = (i0 > 128) ? (i0 - 128) : 0;

    unsigned short* Pw = Pl[wave];
    {
        int row = lane >> 2, col = 144 + (lane & 3) * 4;
        *(uint2*)&Pw[row * 168 + col] = make_uint2(0u, 0u);
    }

    const unsigned short* qrow = qb + rowbase + (size_t)(i0 + l15) * D_ + g * 8;
    const s16x8 aq0 = *(const s16x8*)(qrow);
    const s16x8 aq1 = *(const s16x8*)(qrow + 32);

    f32x4 sacc[9];
    #pragma unroll
    for (int t = 0; t < 9; ++t)
        #pragma unroll
        for (int r = 0; r < 4; ++r) sacc[t][r] = 0.f;

    const unsigned short* kbase = kb + rowbase;
    #pragma unroll
    for (int t = 0; t < 9; ++t) {
        const unsigned short* krow = kbase + (size_t)(klo + t * 16 + l15) * D_ + g * 8;
        s16x8 b0 = *(const s16x8*)(krow);
        s16x8 b1 = *(const s16x8*)(krow + 32);
        sacc[t] = __builtin_amdgcn_mfma_f32_16x16x32_bf16(aq0, b0, sacc[t], 0, 0, 0);
        sacc[t] = __builtin_amdgcn_mfma_f32_16x16x32_bf16(aq1, b1, sacc[t], 0, 0, 0);
    }

    float mrow[4] = {-1e30f, -1e30f, -1e30f, -1e30f};
    #pragma unroll
    for (int t = 0; t < 9; ++t)
        #pragma unroll
        for (int r = 0; r < 4; ++r) {
            const int j  = klo + t * 16 + l15;
            const int iq = i0 + g * 4 + r;
            const bool valid = (j <= iq) && (j + 128 >= iq);
            const float s = valid ? sacc[t][r] * 0.125f : -1e30f;
            sacc[t][r] = s;
            mrow[r] = fmaxf(mrow[r], s);
        }
    #pragma unroll
    for (int r = 0; r < 4; ++r)
        #pragma unroll
        for (int off = 1; off < 16; off <<= 1)
            mrow[r] = fmaxf(mrow[r], __shfl_xor(mrow[r], off));

    float lrow[4] = {0.f, 0.f, 0.f, 0.f};
    #pragma unroll
    for (int t = 0; t < 9; ++t)
        #pragma unroll
        for (int r = 0; r < 4; ++r) {
            const float p = __expf(sacc[t][r] - mrow[r]);
            sacc[t][r] = p;
            lrow[r] += p;
        }
    #pragma unroll
    for (int r = 0; r < 4; ++r) {
        #pragma unroll
        for (int off = 1; off < 16; off <<= 1)
            lrow[r] += __shfl_xor(lrow[r], off);
    }
    float invl[4];
    #pragma unroll
    for (int r = 0; r < 4; ++r) invl[r] = 1.f / lrow[r];

    #pragma unroll
    for (int t = 0; t < 9; ++t)
        #pragma unroll
        for (int r = 0; r < 4; ++r)
            Pw[(g * 4 + r) * 168 + t * 16 + l15] = f2bf(sacc[t][r]);

    f32x4 oacc[4];
    #pragma unroll
    for (int nt = 0; nt < 4; ++nt)
        #pragma unroll
        for (int r = 0; r < 4; ++r) oacc[nt][r] = 0.f;

    const unsigned short* vtb = vt + (size_t)bh * 64 * T_;
    #pragma unroll
    for (int kt = 0; kt < 5; ++kt) {
        const s16x8 ap = *(const s16x8*)&Pw[l15 * 168 + kt * 32 + g * 8];
        #pragma unroll
        for (int nt = 0; nt < 4; ++nt) {
            const unsigned short* vrow = vtb + (size_t)(nt * 16 + l15) * T_ + klo + kt * 32 + g * 8;
            s16x8 bv = *(const s16x8*)vrow;
            oacc[nt] = __builtin_amdgcn_mfma_f32_16x16x32_bf16(ap, bv, oacc[nt], 0, 0, 0);
        }
    }

    #pragma unroll
    for (int nt = 0; nt < 4; ++nt)
        #pragma unroll
        for (int r = 0; r < 4; ++r) {
            const float val = oacc[nt][r] * invl[r];
            ob[rowbase + (size_t)(i0 + g * 4 + r) * D_ + nt * 16 + l15] = f2bf(val);
        }
}

extern "C" void kernel_launch(void* const* d_in, const int* in_sizes, int n_in,
                              void* d_out, int out_size, void* d_ws, size_t ws_size,
                              hipStream_t stream) {
    const float* x  = (const float*)d_in[0];
    const float* Wq = (const float*)d_in[1];
    const float* Wk = (const float*)d_in[2];
    const float* Wv = (const float*)d_in[3];
    const float* Wo = (const float*)d_in[4];

    const size_t MD = (size_t)M_ * D_;      // 4,194,304
    const size_t WN = (size_t)D_ * D_;      // 1,048,576

    // ws (bf16): xb | Wqb | Wkb | Wvb | Wob | qb | vb = 16M elems = 32 MB
    unsigned short* wsb = (unsigned short*)d_ws;
    unsigned short* xb  = wsb;
    unsigned short* Wqb = xb + MD;          // Wq|Wk|Wv adjacent = merged B matrix
    unsigned short* Wob = Wqb + 3 * WN;
    unsigned short* qb  = Wob + WN;
    unsigned short* vb  = qb + MD;
    // d_out doubles as vt | kb until the final GEMM overwrites it.
    // vt FIRST: its benign 16-elem tail over-read lands in kb, not past d_out.
    unsigned short* vt = (unsigned short*)d_out;
    unsigned short* kb = vt + MD;

    conv_bf16<<<8192, 256, 0, stream>>>(x, Wq, Wk, Wv, Wo, wsb);

    // merged QKV projection: N = 3072, 768 blocks (3/CU)
    gemm_m97<unsigned short><<<dim3(24, M_ / 128), 256, 0, stream>>>(
        xb, Wqb, qb, kb, vb, D_);
    transpose_bh<<<dim3(T_ / 64, B_ * H_), 256, 0, stream>>>(vb, vt);

    swa_mfma<<<(B_ * H_ * T_ / 16) / 4, 256, 0, stream>>>(qb, kb, vt, qb);

    // output projection: N = 1024
    gemm_m97<float><<<dim3(8, M_ / 128), 256, 0, stream>>>(
        qb, Wob, (float*)d_out, (float*)d_out, (float*)d_out, D_);
}

// Round 7
// 164.193 us; speedup vs baseline: 6.8736x; 1.0604x over previous
//
#include <hip/hip_runtime.h>
#include <hip/hip_bf16.h>

#define B_  2
#define T_  2048
#define D_  1024
#define H_  16
#define DH_ 64
#define M_  (B_ * T_)   // 4096 rows

typedef short s16x8 __attribute__((ext_vector_type(8)));
typedef float f32x4 __attribute__((ext_vector_type(4)));

__device__ inline float bfu(unsigned short u) {
    union { unsigned int i; float f; } c; c.i = ((unsigned int)u) << 16; return c.f;
}
__device__ inline unsigned short f2bf(float f) {   // round-to-nearest-even
    union { float f; unsigned int i; } c; c.f = f;
    unsigned int r = c.i + 0x7fffu + ((c.i >> 16) & 1u);
    return (unsigned short)(r >> 16);
}
__device__ inline void stv(float* p, float v) { *p = v; }
__device__ inline void stv(unsigned short* p, float v) { *p = f2bf(v); }

// async global->LDS, 16B per lane; lds base must be wave-uniform (HW adds lane*16)
__device__ inline void gload_lds16(const unsigned short* g, unsigned short* l) {
    __builtin_amdgcn_global_load_lds(
        (const __attribute__((address_space(1))) void*)g,
        (__attribute__((address_space(3))) void*)l, 16, 0, 0);
}

// ---------------------------------------------------------------------------
// fp32 -> bf16 conversion of x and the 4 weights into one contiguous ws blob.
// ---------------------------------------------------------------------------
__global__ __launch_bounds__(256) void conv_bf16(const float* __restrict__ x,
                                                 const float* __restrict__ Wq,
                                                 const float* __restrict__ Wk,
                                                 const float* __restrict__ Wv,
                                                 const float* __restrict__ Wo,
                                                 unsigned short* __restrict__ dst) {
    const int g = blockIdx.x * 256 + threadIdx.x;       // 0 .. 2^21-1
    const float* s; size_t o;
    if (g < (1 << 20)) { s = x; o = (size_t)g; }
    else {
        int gg = g - (1 << 20);
        int w = gg >> 18;
        o = (size_t)(gg & ((1 << 18) - 1));
        s = (w == 0) ? Wq : (w == 1) ? Wk : (w == 2) ? Wv : Wo;
    }
    float4 v = ((const float4*)s)[o];
    ushort4 u;
    u.x = f2bf(v.x); u.y = f2bf(v.y); u.z = f2bf(v.z); u.w = f2bf(v.w);
    ((ushort4*)dst)[g] = u;
}

// ---------------------------------------------------------------------------
// m97-style MFMA NT GEMM (bf16 in, fp32 acc): C[m,n] = sum_k A[m,k]*Bw[n,k].
// BM x 128 tile (BM=128 or 64), BK=32, 256 thr (2x2 waves), 16x16x32 MFMA.
// Staging: global_load_lds width=16, unpadded LDS rows (32 ushorts = 64 B).
// Output row stride fixed 1024; buffer selected per 128-wide n-tile (bn/1024)
// so one launch computes x@[Wq|Wk|Wv]^T into q/k/v.
// ---------------------------------------------------------------------------
template <int BM, typename Tout>
__global__ __launch_bounds__(256) void gemm_m97(const unsigned short* __restrict__ A,
                                                const unsigned short* __restrict__ Bw,
                                                Tout* __restrict__ C0,
                                                Tout* __restrict__ C1,
                                                Tout* __restrict__ C2,
                                                int K) {
    constexpr int MI = BM / 32;                   // m-frags per wave
    __shared__ unsigned short As[BM * 32];
    __shared__ unsigned short Bs[128 * 32];
    const int tid  = threadIdx.x;
    const int lane = tid & 63;
    const int wave = tid >> 6;
    const int wr = wave >> 1, wc = wave & 1;
    const int bm = blockIdx.y * BM, bn = blockIdx.x * 128;
    const int fr = lane & 15, kg = lane >> 4;
    const int lrow = lane >> 2;          // staging row within 16-row window
    const int lcol = (lane & 3) * 8;     // staging 16B chunk (ushort offset)

    f32x4 acc[MI][4];
    #pragma unroll
    for (int mi = 0; mi < MI; ++mi)
        #pragma unroll
        for (int ni = 0; ni < 4; ++ni)
            #pragma unroll
            for (int r = 0; r < 4; ++r) acc[mi][ni][r] = 0.f;

    const unsigned short* ga = A  + (size_t)(bm + wave * 16 + lrow) * K + lcol;
    const unsigned short* gb = Bw + (size_t)(bn + wave * 16 + lrow) * K + lcol;
    unsigned short* la = &As[(wave * 16) * 32];   // wave-uniform
    unsigned short* lb = &Bs[(wave * 16) * 32];

    for (int k0 = 0; k0 < K; k0 += 32) {
        __syncthreads();                          // prev-iter LDS reads done
        #pragma unroll
        for (int s = 0; s < BM / 64; ++s)
            gload_lds16(ga + k0 + (size_t)(s * 64) * K, la + s * 64 * 32);
        gload_lds16(gb + k0,                  lb);
        gload_lds16(gb + k0 + (size_t)64 * K, lb + 64 * 32);
        __syncthreads();                          // vmcnt drained: tile visible
        s16x8 af[MI], bfv[4];
        #pragma unroll
        for (int mi = 0; mi < MI; ++mi)
            af[mi] = *(const s16x8*)&As[(wr * (BM / 2) + mi * 16 + fr) * 32 + kg * 8];
        #pragma unroll
        for (int ni = 0; ni < 4; ++ni)
            bfv[ni] = *(const s16x8*)&Bs[(wc * 64 + ni * 16 + fr) * 32 + kg * 8];
        #pragma unroll
        for (int mi = 0; mi < MI; ++mi)
            #pragma unroll
            for (int ni = 0; ni < 4; ++ni)
                acc[mi][ni] = __builtin_amdgcn_mfma_f32_16x16x32_bf16(af[mi], bfv[ni], acc[mi][ni], 0, 0, 0);
    }

    Tout* C = (bn < 1024) ? C0 : (bn < 2048) ? C1 : C2;
    const int nb = bn & 1023;
    #pragma unroll
    for (int mi = 0; mi < MI; ++mi)
        #pragma unroll
        for (int ni = 0; ni < 4; ++ni)
            #pragma unroll
            for (int r = 0; r < 4; ++r) {
                int m = bm + wr * (BM / 2) + mi * 16 + kg * 4 + r;
                int n = nb + wc * 64 + ni * 16 + fr;
                stv(&C[(size_t)m * 1024 + n], acc[mi][ni][r]);
            }
}

// ---------------------------------------------------------------------------
// Transpose per (b,h): src[(b*T+t)*D + h*64 + d] -> dst[(b*H+h)*64 + d][t].
// ---------------------------------------------------------------------------
__global__ __launch_bounds__(256) void transpose_bh(const unsigned short* __restrict__ src0,
                                                    unsigned short* __restrict__ dst) {
    __shared__ unsigned short sm[64][66];
    const int tid = threadIdx.x;
    const int t0 = blockIdx.x * 64;
    const int bh = blockIdx.y;
    const int b = bh >> 4, h = bh & 15;
    const unsigned short* src = src0 + ((size_t)(b * T_ + t0)) * D_ + h * 64;
    #pragma unroll
    for (int kc = 0; kc < 16; ++kc) {
        int idx = kc * 256 + tid;
        int r = idx >> 6, c = idx & 63;
        sm[r][c] = src[(size_t)r * D_ + c];
    }
    __syncthreads();
    unsigned short* d2 = dst + (size_t)bh * 64 * T_ + t0;
    #pragma unroll
    for (int kc = 0; kc < 16; ++kc) {
        int idx = kc * 256 + tid;
        int d = idx >> 6, tt = idx & 63;
        d2[(size_t)d * T_ + tt] = sm[tt][d];
    }
}

// ---------------------------------------------------------------------------
// MFMA sliding-window attention v2. Block = 64 consecutive queries of one
// (b,h), 4 waves x 16 queries (fragment layouts identical to validated r5).
// NEW: block-shared K window [klo2, klo2+191] staged once into LDS via
// global_load_lds (24 x 1KB async), QK^T B-frags via ds_read_b128 (2-way
// bank aliasing = free). Q and V(t) stay as global reads. P roundtrips
// through per-wave LDS as before. o==q in-place safe (wave-private rows).
// ---------------------------------------------------------------------------
__global__ __launch_bounds__(256) void swa_mfma2(const unsigned short* qb,
                                                 const unsigned short* __restrict__ kb,
                                                 const unsigned short* __restrict__ vt,
                                                 unsigned short* ob) {
    __shared__ unsigned short Ks[192 * 64];        // 24 KB K window
    __shared__ unsigned short Pl[4][16 * 168];     // per-wave P
    const int wave = threadIdx.x >> 6;
    const int lane = threadIdx.x & 63;
    const int blk = blockIdx.x;                    // 0..1023
    const int i0b = (blk & 31) * 64;               // block's first query
    const int bh  = blk >> 5;
    const int h = bh & (H_ - 1), b = bh >> 4;
    const int g = lane >> 4, l15 = lane & 15;

    const size_t rowbase = (size_t)b * T_ * D_ + (size_t)h * DH_;
    const int klo2 = (i0b > 128) ? (i0b - 128) : 0;   // always <= 1856

    // ---- stage K rows [klo2 .. klo2+191] (valid memory for all blocks) ----
    {
        const unsigned short* kg0 = kb + rowbase
            + (size_t)(klo2 + (lane >> 3)) * D_ + (lane & 7) * 8;
        #pragma unroll
        for (int s = 0; s < 6; ++s) {
            const int i = wave * 6 + s;            // 24 instrs, 8 rows each
            gload_lds16(kg0 + (size_t)(i * 8) * D_, &Ks[i * 8 * 64]);
        }
    }

    const int i0  = i0b + wave * 16;
    const int klo = (i0 > 128) ? (i0 - 128) : 0;
    const int koff = klo - klo2;                   // 0..48

    unsigned short* Pw = Pl[wave];
    {   // zero-pad P cols 144..159 (read by last PV k-tile)
        int row = lane >> 2, col = 144 + (lane & 3) * 4;
        *(uint2*)&Pw[row * 168 + col] = make_uint2(0u, 0u);
    }

    // Q fragments (issued before barrier to overlap with K staging)
    const unsigned short* qrow = qb + rowbase + (size_t)(i0 + l15) * D_ + g * 8;
    const s16x8 aq0 = *(const s16x8*)(qrow);
    const s16x8 aq1 = *(const s16x8*)(qrow + 32);

    __syncthreads();                               // K window visible

    // ---- S = Q K^T over 9 key tiles (B-frags from LDS) ----
    f32x4 sacc[9];
    #pragma unroll
    for (int t = 0; t < 9; ++t)
        #pragma unroll
        for (int r = 0; r < 4; ++r) sacc[t][r] = 0.f;

    #pragma unroll
    for (int t = 0; t < 9; ++t) {
        const unsigned short* kr = &Ks[(koff + t * 16 + l15) * 64 + g * 8];
        s16x8 b0 = *(const s16x8*)kr;
        s16x8 b1 = *(const s16x8*)(kr + 32);
        sacc[t] = __builtin_amdgcn_mfma_f32_16x16x32_bf16(aq0, b0, sacc[t], 0, 0, 0);
        sacc[t] = __builtin_amdgcn_mfma_f32_16x16x32_bf16(aq1, b1, sacc[t], 0, 0, 0);
    }

    // ---- mask + scale + softmax (C/D layout: row g*4+r, col l15) ----
    float mrow[4] = {-1e30f, -1e30f, -1e30f, -1e30f};
    #pragma unroll
    for (int t = 0; t < 9; ++t)
        #pragma unroll
        for (int r = 0; r < 4; ++r) {
            const int j  = klo + t * 16 + l15;
            const int iq = i0 + g * 4 + r;
            const bool valid = (j <= iq) && (j + 128 >= iq);
            const float s = valid ? sacc[t][r] * 0.125f : -1e30f;
            sacc[t][r] = s;
            mrow[r] = fmaxf(mrow[r], s);
        }
    #pragma unroll
    for (int r = 0; r < 4; ++r)
        #pragma unroll
        for (int off = 1; off < 16; off <<= 1)
            mrow[r] = fmaxf(mrow[r], __shfl_xor(mrow[r], off));

    float lrow[4] = {0.f, 0.f, 0.f, 0.f};
    #pragma unroll
    for (int t = 0; t < 9; ++t)
        #pragma unroll
        for (int r = 0; r < 4; ++r) {
            const float p = __expf(sacc[t][r] - mrow[r]);
            sacc[t][r] = p;
            lrow[r] += p;
        }
    #pragma unroll
    for (int r = 0; r < 4; ++r) {
        #pragma unroll
        for (int off = 1; off < 16; off <<= 1)
            lrow[r] += __shfl_xor(lrow[r], off);
    }
    float invl[4];
    #pragma unroll
    for (int r = 0; r < 4; ++r) invl[r] = 1.f / lrow[r];

    // ---- P (bf16) -> per-wave LDS (same-wave ordering, no barrier) ----
    #pragma unroll
    for (int t = 0; t < 9; ++t)
        #pragma unroll
        for (int r = 0; r < 4; ++r)
            Pw[(g * 4 + r) * 168 + t * 16 + l15] = f2bf(sacc[t][r]);

    // ---- O = P V : A = P from LDS, B = V^T rows from global (d-major) ----
    f32x4 oacc[4];
    #pragma unroll
    for (int nt = 0; nt < 4; ++nt)
        #pragma unroll
        for (int r = 0; r < 4; ++r) oacc[nt][r] = 0.f;

    const unsigned short* vtb = vt + (size_t)bh * 64 * T_;
    #pragma unroll
    for (int kt = 0; kt < 5; ++kt) {
        const s16x8 ap = *(const s16x8*)&Pw[l15 * 168 + kt * 32 + g * 8];
        #pragma unroll
        for (int nt = 0; nt < 4; ++nt) {
            const unsigned short* vrow = vtb + (size_t)(nt * 16 + l15) * T_ + klo + kt * 32 + g * 8;
            s16x8 bv = *(const s16x8*)vrow;
            oacc[nt] = __builtin_amdgcn_mfma_f32_16x16x32_bf16(ap, bv, oacc[nt], 0, 0, 0);
        }
    }

    #pragma unroll
    for (int nt = 0; nt < 4; ++nt)
        #pragma unroll
        for (int r = 0; r < 4; ++r) {
            const float val = oacc[nt][r] * invl[r];
            ob[rowbase + (size_t)(i0 + g * 4 + r) * D_ + nt * 16 + l15] = f2bf(val);
        }
}

extern "C" void kernel_launch(void* const* d_in, const int* in_sizes, int n_in,
                              void* d_out, int out_size, void* d_ws, size_t ws_size,
                              hipStream_t stream) {
    const float* x  = (const float*)d_in[0];
    const float* Wq = (const float*)d_in[1];
    const float* Wk = (const float*)d_in[2];
    const float* Wv = (const float*)d_in[3];
    const float* Wo = (const float*)d_in[4];

    const size_t MD = (size_t)M_ * D_;      // 4,194,304
    const size_t WN = (size_t)D_ * D_;      // 1,048,576

    // ws (bf16): xb | Wqb | Wkb | Wvb | Wob | qb | vb = 16M elems = 32 MB
    unsigned short* wsb = (unsigned short*)d_ws;
    unsigned short* xb  = wsb;
    unsigned short* Wqb = xb + MD;          // Wq|Wk|Wv adjacent = merged B matrix
    unsigned short* Wob = Wqb + 3 * WN;
    unsigned short* qb  = Wob + WN;
    unsigned short* vb  = qb + MD;
    // d_out doubles as vt | kb until the final GEMM overwrites it.
    // vt FIRST: its benign 16-elem tail over-read lands in kb, not past d_out.
    unsigned short* vt = (unsigned short*)d_out;
    unsigned short* kb = vt + MD;

    conv_bf16<<<8192, 256, 0, stream>>>(x, Wq, Wk, Wv, Wo, wsb);

    // merged QKV projection: N = 3072, 768 blocks (3/CU)
    gemm_m97<128, unsigned short><<<dim3(24, M_ / 128), 256, 0, stream>>>(
        xb, Wqb, qb, kb, vb, D_);
    transpose_bh<<<dim3(T_ / 64, B_ * H_), 256, 0, stream>>>(vb, vt);

    swa_mfma2<<<(B_ * H_ * T_) / 64, 256, 0, stream>>>(qb, kb, vt, qb);

    // output projection: N = 1024, 64-row M-tiles -> 512 blocks (2/CU)
    gemm_m97<64, float><<<dim3(8, M_ / 64), 256, 0, stream>>>(
        qb, Wob, (float*)d_out, (float*)d_out, (float*)d_out, D_);
}

// Round 9
// 156.419 us; speedup vs baseline: 7.2152x; 1.0497x over previous
//
#include <hip/hip_runtime.h>
#include <hip/hip_bf16.h>

#define B_  2
#define T_  2048
#define D_  1024
#define H_  16
#define DH_ 64
#define M_  (B_ * T_)   // 4096 rows

typedef short s16x8 __attribute__((ext_vector_type(8)));
typedef float f32x4 __attribute__((ext_vector_type(4)));

__device__ inline float bfu(unsigned short u) {
    union { unsigned int i; float f; } c; c.i = ((unsigned int)u) << 16; return c.f;
}
__device__ inline unsigned short f2bf(float f) {   // round-to-nearest-even
    union { float f; unsigned int i; } c; c.f = f;
    unsigned int r = c.i + 0x7fffu + ((c.i >> 16) & 1u);
    return (unsigned short)(r >> 16);
}
__device__ inline void stv(float* p, float v) { *p = v; }
__device__ inline void stv(unsigned short* p, float v) { *p = f2bf(v); }

// async global->LDS, 16B per lane; lds base must be wave-uniform (HW adds lane*16)
__device__ inline void gload_lds16(const unsigned short* g, unsigned short* l) {
    __builtin_amdgcn_global_load_lds(
        (const __attribute__((address_space(1))) void*)g,
        (__attribute__((address_space(3))) void*)l, 16, 0, 0);
}

// ---------------------------------------------------------------------------
// fp32 -> bf16 conversion of x and the 4 weights into one contiguous ws blob.
// ---------------------------------------------------------------------------
__global__ __launch_bounds__(256) void conv_bf16(const float* __restrict__ x,
                                                 const float* __restrict__ Wq,
                                                 const float* __restrict__ Wk,
                                                 const float* __restrict__ Wv,
                                                 const float* __restrict__ Wo,
                                                 unsigned short* __restrict__ dst) {
    const int g = blockIdx.x * 256 + threadIdx.x;       // 0 .. 2^21-1
    const float* s; size_t o;
    if (g < (1 << 20)) { s = x; o = (size_t)g; }
    else {
        int gg = g - (1 << 20);
        int w = gg >> 18;
        o = (size_t)(gg & ((1 << 18) - 1));
        s = (w == 0) ? Wq : (w == 1) ? Wk : (w == 2) ? Wv : Wo;
    }
    float4 v = ((const float4*)s)[o];
    ushort4 u;
    u.x = f2bf(v.x); u.y = f2bf(v.y); u.z = f2bf(v.z); u.w = f2bf(v.w);
    ((ushort4*)dst)[g] = u;
}

// ---------------------------------------------------------------------------
// m97-style MFMA NT GEMM, BK=64 as two stacked BK=32 half-tiles (same LDS row
// layout as BK=32 -> glld-compatible, conflict pattern unchanged; half the
// barriers, 32 MFMAs per drain). BM x 128 tile, 256 thr (2x2 waves of
// (BM/2)x64), 16x16x32 MFMA, fp32 acc.
// Output: row stride 1024, buffer per 128-wide n-tile: bn<1024 -> C0,
// bn<2048 -> C1, bn>=2048 (only when vtr != null) -> V written TRANSPOSED
// to vtr[(b*16+h)*64+d][t] (packed ushort4: r = 4 consecutive t).
// ---------------------------------------------------------------------------
template <int BM, typename Tout>
__global__ __launch_bounds__(256) void gemm_m97(const unsigned short* __restrict__ A,
                                                const unsigned short* __restrict__ Bw,
                                                Tout* __restrict__ C0,
                                                Tout* __restrict__ C1,
                                                unsigned short* __restrict__ vtr,
                                                int K) {
    constexpr int MI = BM / 32;                   // m-frags per wave
    __shared__ unsigned short As[2 * BM * 32];    // [half][BM][32]
    __shared__ unsigned short Bs[2 * 128 * 32];   // [half][128][32]
    const int tid  = threadIdx.x;
    const int lane = tid & 63;
    const int wave = tid >> 6;
    const int wr = wave >> 1, wc = wave & 1;
    const int bm = blockIdx.y * BM, bn = blockIdx.x * 128;
    const int fr = lane & 15, kg = lane >> 4;
    const int lrow = lane >> 2;          // staging row within 16-row window
    const int lcol = (lane & 3) * 8;     // staging 16B chunk (ushort offset)

    f32x4 acc[MI][4];
    #pragma unroll
    for (int mi = 0; mi < MI; ++mi)
        #pragma unroll
        for (int ni = 0; ni < 4; ++ni)
            #pragma unroll
            for (int r = 0; r < 4; ++r) acc[mi][ni][r] = 0.f;

    const unsigned short* ga = A  + (size_t)(bm + wave * 16 + lrow) * K + lcol;
    const unsigned short* gb = Bw + (size_t)(bn + wave * 16 + lrow) * K + lcol;
    unsigned short* la = &As[(wave * 16) * 32];   // wave-uniform
    unsigned short* lb = &Bs[(wave * 16) * 32];

    for (int k0 = 0; k0 < K; k0 += 64) {
        __syncthreads();                          // prev-iter LDS reads done
        #pragma unroll
        for (int hf = 0; hf < 2; ++hf) {
            #pragma unroll
            for (int s = 0; s < BM / 64; ++s)
                gload_lds16(ga + k0 + hf * 32 + (size_t)(s * 64) * K,
                            la + hf * BM * 32 + s * 64 * 32);
            gload_lds16(gb + k0 + hf * 32,                  lb + hf * 128 * 32);
            gload_lds16(gb + k0 + hf * 32 + (size_t)64 * K, lb + hf * 128 * 32 + 64 * 32);
        }
        __syncthreads();                          // vmcnt drained: tile visible
        #pragma unroll
        for (int hf = 0; hf < 2; ++hf) {
            s16x8 af[MI], bfv[4];
            #pragma unroll
            for (int mi = 0; mi < MI; ++mi)
                af[mi] = *(const s16x8*)&As[hf * BM * 32 + (wr * (BM / 2) + mi * 16 + fr) * 32 + kg * 8];
            #pragma unroll
            for (int ni = 0; ni < 4; ++ni)
                bfv[ni] = *(const s16x8*)&Bs[hf * 128 * 32 + (wc * 64 + ni * 16 + fr) * 32 + kg * 8];
            #pragma unroll
            for (int mi = 0; mi < MI; ++mi)
                #pragma unroll
                for (int ni = 0; ni < 4; ++ni)
                    acc[mi][ni] = __builtin_amdgcn_mfma_f32_16x16x32_bf16(af[mi], bfv[ni], acc[mi][ni], 0, 0, 0);
        }
    }

    if (vtr && bn >= 2048) {
        // V n-tile: write transposed, packed over r (4 consecutive t)
        #pragma unroll
        for (int mi = 0; mi < MI; ++mi)
            #pragma unroll
            for (int ni = 0; ni < 4; ++ni) {
                const int nl = (bn - 2048) + wc * 64 + ni * 16 + fr;
                const int h = nl >> 6, d = nl & 63;
                const int m0 = bm + wr * (BM / 2) + mi * 16 + kg * 4;
                const int b = m0 >> 11, t0 = m0 & (T_ - 1);
                ushort4 u;
                u.x = f2bf(acc[mi][ni][0]); u.y = f2bf(acc[mi][ni][1]);
                u.z = f2bf(acc[mi][ni][2]); u.w = f2bf(acc[mi][ni][3]);
                *(ushort4*)(vtr + ((size_t)(b * H_ + h) * 64 + d) * T_ + t0) = u;
            }
        return;
    }
    Tout* C = (bn < 1024) ? C0 : C1;
    const int nb = bn & 1023;
    #pragma unroll
    for (int mi = 0; mi < MI; ++mi)
        #pragma unroll
        for (int ni = 0; ni < 4; ++ni)
            #pragma unroll
            for (int r = 0; r < 4; ++r) {
                int m = bm + wr * (BM / 2) + mi * 16 + kg * 4 + r;
                int n = nb + wc * 64 + ni * 16 + fr;
                stv(&C[(size_t)m * 1024 + n], acc[mi][ni][r]);
            }
}

// ---------------------------------------------------------------------------
// MFMA sliding-window attention v2 (validated round 7). Block = 64 queries of
// one (b,h); K window [klo2, klo2+191] staged via global_load_lds.
// ---------------------------------------------------------------------------
__global__ __launch_bounds__(256) void swa_mfma2(const unsigned short* qb,
                                                 const unsigned short* __restrict__ kb,
                                                 const unsigned short* __restrict__ vt,
                                                 unsigned short* ob) {
    __shared__ unsigned short Ks[192 * 64];        // 24 KB K window
    __shared__ unsigned short Pl[4][16 * 168];     // per-wave P
    const int wave = threadIdx.x >> 6;
    const int lane = threadIdx.x & 63;
    const int blk = blockIdx.x;                    // 0..1023
    const int i0b = (blk & 31) * 64;               // block's first query
    const int bh  = blk >> 5;
    const int h = bh & (H_ - 1), b = bh >> 4;
    const int g = lane >> 4, l15 = lane & 15;

    const size_t rowbase = (size_t)b * T_ * D_ + (size_t)h * DH_;
    const int klo2 = (i0b > 128) ? (i0b - 128) : 0;   // always <= 1856

    {
        const unsigned short* kg0 = kb + rowbase
            + (size_t)(klo2 + (lane >> 3)) * D_ + (lane & 7) * 8;
        #pragma unroll
        for (int s = 0; s < 6; ++s) {
            const int i = wave * 6 + s;            // 24 instrs, 8 rows each
            gload_lds16(kg0 + (size_t)(i * 8) * D_, &Ks[i * 8 * 64]);
        }
    }

    const int i0  = i0b + wave * 16;
    const int klo = (i0 > 128) ? (i0 - 128) : 0;
    const int koff = klo - klo2;                   // 0..48

    unsigned short* Pw = Pl[wave];
    {   // zero-pad P cols 144..159 (read by last PV k-tile)
        int row = lane >> 2, col = 144 + (lane & 3) * 4;
        *(uint2*)&Pw[row * 168 + col] = make_uint2(0u, 0u);
    }

    const unsigned short* qrow = qb + rowbase + (size_t)(i0 + l15) * D_ + g * 8;
    const s16x8 aq0 = *(const s16x8*)(qrow);
    const s16x8 aq1 = *(const s16x8*)(qrow + 32);

    __syncthreads();                               // K window visible

    f32x4 sacc[9];
    #pragma unroll
    for (int t = 0; t < 9; ++t)
        #pragma unroll
        for (int r = 0; r < 4; ++r) sacc[t][r] = 0.f;

    #pragma unroll
    for (int t = 0; t < 9; ++t) {
        const unsigned short* kr = &Ks[(koff + t * 16 + l15) * 64 + g * 8];
        s16x8 b0 = *(const s16x8*)kr;
        s16x8 b1 = *(const s16x8*)(kr + 32);
        sacc[t] = __builtin_amdgcn_mfma_f32_16x16x32_bf16(aq0, b0, sacc[t], 0, 0, 0);
        sacc[t] = __builtin_amdgcn_mfma_f32_16x16x32_bf16(aq1, b1, sacc[t], 0, 0, 0);
    }

    float mrow[4] = {-1e30f, -1e30f, -1e30f, -1e30f};
    #pragma unroll
    for (int t = 0; t < 9; ++t)
        #pragma unroll
        for (int r = 0; r < 4; ++r) {
            const int j  = klo + t * 16 + l15;
            const int iq = i0 + g * 4 + r;
            const bool valid = (j <= iq) && (j + 128 >= iq);
            const float s = valid ? sacc[t][r] * 0.125f : -1e30f;
            sacc[t][r] = s;
            mrow[r] = fmaxf(mrow[r], s);
        }
    #pragma unroll
    for (int r = 0; r < 4; ++r)
        #pragma unroll
        for (int off = 1; off < 16; off <<= 1)
            mrow[r] = fmaxf(mrow[r], __shfl_xor(mrow[r], off));

    float lrow[4] = {0.f, 0.f, 0.f, 0.f};
    #pragma unroll
    for (int t = 0; t < 9; ++t)
        #pragma unroll
        for (int r = 0; r < 4; ++r) {
            const float p = __expf(sacc[t][r] - mrow[r]);
            sacc[t][r] = p;
            lrow[r] += p;
        }
    #pragma unroll
    for (int r = 0; r < 4; ++r) {
        #pragma unroll
        for (int off = 1; off < 16; off <<= 1)
            lrow[r] += __shfl_xor(lrow[r], off);
    }
    float invl[4];
    #pragma unroll
    for (int r = 0; r < 4; ++r) invl[r] = 1.f / lrow[r];

    #pragma unroll
    for (int t = 0; t < 9; ++t)
        #pragma unroll
        for (int r = 0; r < 4; ++r)
            Pw[(g * 4 + r) * 168 + t * 16 + l15] = f2bf(sacc[t][r]);

    f32x4 oacc[4];
    #pragma unroll
    for (int nt = 0; nt < 4; ++nt)
        #pragma unroll
        for (int r = 0; r < 4; ++r) oacc[nt][r] = 0.f;

    const unsigned short* vtb = vt + (size_t)bh * 64 * T_;
    #pragma unroll
    for (int kt = 0; kt < 5; ++kt) {
        const s16x8 ap = *(const s16x8*)&Pw[l15 * 168 + kt * 32 + g * 8];
        #pragma unroll
        for (int nt = 0; nt < 4; ++nt) {
            const unsigned short* vrow = vtb + (size_t)(nt * 16 + l15) * T_ + klo + kt * 32 + g * 8;
            s16x8 bv = *(const s16x8*)vrow;
            oacc[nt] = __builtin_amdgcn_mfma_f32_16x16x32_bf16(ap, bv, oacc[nt], 0, 0, 0);
        }
    }

    #pragma unroll
    for (int nt = 0; nt < 4; ++nt)
        #pragma unroll
        for (int r = 0; r < 4; ++r) {
            const float val = oacc[nt][r] * invl[r];
            ob[rowbase + (size_t)(i0 + g * 4 + r) * D_ + nt * 16 + l15] = f2bf(val);
        }
}

extern "C" void kernel_launch(void* const* d_in, const int* in_sizes, int n_in,
                              void* d_out, int out_size, void* d_ws, size_t ws_size,
                              hipStream_t stream) {
    const float* x  = (const float*)d_in[0];
    const float* Wq = (const float*)d_in[1];
    const float* Wk = (const float*)d_in[2];
    const float* Wv = (const float*)d_in[3];
    const float* Wo = (const float*)d_in[4];

    const size_t MD = (size_t)M_ * D_;      // 4,194,304
    const size_t WN = (size_t)D_ * D_;      // 1,048,576

    // ws (bf16): xb | Wqb|Wkb|Wvb | Wob | qb  = 24 MB
    unsigned short* wsb = (unsigned short*)d_ws;
    unsigned short* xb  = wsb;
    unsigned short* Wqb = xb + MD;          // Wq|Wk|Wv adjacent = merged B matrix
    unsigned short* Wob = Wqb + 3 * WN;
    unsigned short* qb  = Wob + WN;
    // d_out doubles as vt | kb until the final GEMM overwrites it.
    // vt FIRST: swa's PV reads stay within [0, 4M) elems of vt exactly.
    unsigned short* vt = (unsigned short*)d_out;
    unsigned short* kb = vt + MD;

    conv_bf16<<<8192, 256, 0, stream>>>(x, Wq, Wk, Wv, Wo, wsb);

    // merged QKV projection: N = 3072, 768 blocks (3/CU); V written transposed
    gemm_m97<128, unsigned short><<<dim3(24, M_ / 128), 256, 0, stream>>>(
        xb, Wqb, qb, kb, vt, D_);

    swa_mfma2<<<(B_ * H_ * T_) / 64, 256, 0, stream>>>(qb, kb, vt, qb);

    // output projection: N = 1024, 64-row M-tiles -> 512 blocks (2/CU)
    gemm_m97<64, float><<<dim3(8, M_ / 64), 256, 0, stream>>>(
        qb, Wob, (float*)d_out, (float*)d_out, nullptr, D_);
}

// Round 10
// 149.421 us; speedup vs baseline: 7.5531x; 1.0468x over previous
//
#include <hip/hip_runtime.h>
#include <hip/hip_bf16.h>

#define B_  2
#define T_  2048
#define D_  1024
#define H_  16
#define DH_ 64
#define M_  (B_ * T_)   // 4096 rows

typedef short s16x8 __attribute__((ext_vector_type(8)));
typedef float f32x4 __attribute__((ext_vector_type(4)));

__device__ inline float bfu(unsigned short u) {
    union { unsigned int i; float f; } c; c.i = ((unsigned int)u) << 16; return c.f;
}
__device__ inline unsigned short f2bf(float f) {   // round-to-nearest-even
    union { float f; unsigned int i; } c; c.f = f;
    unsigned int r = c.i + 0x7fffu + ((c.i >> 16) & 1u);
    return (unsigned short)(r >> 16);
}
__device__ inline void stv(float* p, float v) { *p = v; }
__device__ inline void stv(unsigned short* p, float v) { *p = f2bf(v); }

// async global->LDS, 16B per lane; lds base must be wave-uniform (HW adds lane*16)
__device__ inline void gload_lds16(const unsigned short* g, unsigned short* l) {
    __builtin_amdgcn_global_load_lds(
        (const __attribute__((address_space(1))) void*)g,
        (__attribute__((address_space(3))) void*)l, 16, 0, 0);
}

// ---------------------------------------------------------------------------
// fp32 -> bf16 conversion of x and the 4 weights into one contiguous ws blob.
// ---------------------------------------------------------------------------
__global__ __launch_bounds__(256) void conv_bf16(const float* __restrict__ x,
                                                 const float* __restrict__ Wq,
                                                 const float* __restrict__ Wk,
                                                 const float* __restrict__ Wv,
                                                 const float* __restrict__ Wo,
                                                 unsigned short* __restrict__ dst) {
    const int g = blockIdx.x * 256 + threadIdx.x;       // 0 .. 2^21-1
    const float* s; size_t o;
    if (g < (1 << 20)) { s = x; o = (size_t)g; }
    else {
        int gg = g - (1 << 20);
        int w = gg >> 18;
        o = (size_t)(gg & ((1 << 18) - 1));
        s = (w == 0) ? Wq : (w == 1) ? Wk : (w == 2) ? Wv : Wo;
    }
    float4 v = ((const float4*)s)[o];
    ushort4 u;
    u.x = f2bf(v.x); u.y = f2bf(v.y); u.z = f2bf(v.z); u.w = f2bf(v.w);
    ((ushort4*)dst)[g] = u;
}

// ---------------------------------------------------------------------------
// m97-style MFMA NT GEMM, BK = 32*NH as NH stacked BK=32 half-tiles (same LDS
// row layout as BK=32 -> glld-compatible; 16*MI MFMAs... per barrier drain:
// NH * MI * 4 MFMAs). BM x 128 tile, 256 thr (2x2 waves), 16x16x32, fp32 acc.
// Output: row stride 1024, buffer per 128-wide n-tile: bn<1024 -> C0,
// bn<2048 -> C1, bn>=2048 (only when vtr != null) -> V written TRANSPOSED
// to vtr[(b*16+h)*64+d][t] (packed ushort4: r = 4 consecutive t).
// ---------------------------------------------------------------------------
template <int BM, int NH, typename Tout>
__global__ __launch_bounds__(256) void gemm_m97(const unsigned short* __restrict__ A,
                                                const unsigned short* __restrict__ Bw,
                                                Tout* __restrict__ C0,
                                                Tout* __restrict__ C1,
                                                unsigned short* __restrict__ vtr,
                                                int K) {
    constexpr int MI = BM / 32;                   // m-frags per wave
    __shared__ unsigned short As[NH * BM * 32];   // [half][BM][32]
    __shared__ unsigned short Bs[NH * 128 * 32];  // [half][128][32]
    const int tid  = threadIdx.x;
    const int lane = tid & 63;
    const int wave = tid >> 6;
    const int wr = wave >> 1, wc = wave & 1;
    const int bm = blockIdx.y * BM, bn = blockIdx.x * 128;
    const int fr = lane & 15, kg = lane >> 4;
    const int lrow = lane >> 2;          // staging row within 16-row window
    const int lcol = (lane & 3) * 8;     // staging 16B chunk (ushort offset)

    f32x4 acc[MI][4];
    #pragma unroll
    for (int mi = 0; mi < MI; ++mi)
        #pragma unroll
        for (int ni = 0; ni < 4; ++ni)
            #pragma unroll
            for (int r = 0; r < 4; ++r) acc[mi][ni][r] = 0.f;

    const unsigned short* ga = A  + (size_t)(bm + wave * 16 + lrow) * K + lcol;
    const unsigned short* gb = Bw + (size_t)(bn + wave * 16 + lrow) * K + lcol;
    unsigned short* la = &As[(wave * 16) * 32];   // wave-uniform
    unsigned short* lb = &Bs[(wave * 16) * 32];

    for (int k0 = 0; k0 < K; k0 += 32 * NH) {
        __syncthreads();                          // prev-iter LDS reads done
        #pragma unroll
        for (int hf = 0; hf < NH; ++hf) {
            #pragma unroll
            for (int s = 0; s < BM / 64; ++s)
                gload_lds16(ga + k0 + hf * 32 + (size_t)(s * 64) * K,
                            la + hf * BM * 32 + s * 64 * 32);
            gload_lds16(gb + k0 + hf * 32,                  lb + hf * 128 * 32);
            gload_lds16(gb + k0 + hf * 32 + (size_t)64 * K, lb + hf * 128 * 32 + 64 * 32);
        }
        __syncthreads();                          // vmcnt drained: tile visible
        #pragma unroll
        for (int hf = 0; hf < NH; ++hf) {
            s16x8 af[MI], bfv[4];
            #pragma unroll
            for (int mi = 0; mi < MI; ++mi)
                af[mi] = *(const s16x8*)&As[hf * BM * 32 + (wr * (BM / 2) + mi * 16 + fr) * 32 + kg * 8];
            #pragma unroll
            for (int ni = 0; ni < 4; ++ni)
                bfv[ni] = *(const s16x8*)&Bs[hf * 128 * 32 + (wc * 64 + ni * 16 + fr) * 32 + kg * 8];
            #pragma unroll
            for (int mi = 0; mi < MI; ++mi)
                #pragma unroll
                for (int ni = 0; ni < 4; ++ni)
                    acc[mi][ni] = __builtin_amdgcn_mfma_f32_16x16x32_bf16(af[mi], bfv[ni], acc[mi][ni], 0, 0, 0);
        }
    }

    if (vtr && bn >= 2048) {
        // V n-tile: write transposed, packed over r (4 consecutive t)
        #pragma unroll
        for (int mi = 0; mi < MI; ++mi)
            #pragma unroll
            for (int ni = 0; ni < 4; ++ni) {
                const int nl = (bn - 2048) + wc * 64 + ni * 16 + fr;
                const int h = nl >> 6, d = nl & 63;
                const int m0 = bm + wr * (BM / 2) + mi * 16 + kg * 4;
                const int b = m0 >> 11, t0 = m0 & (T_ - 1);
                ushort4 u;
                u.x = f2bf(acc[mi][ni][0]); u.y = f2bf(acc[mi][ni][1]);
                u.z = f2bf(acc[mi][ni][2]); u.w = f2bf(acc[mi][ni][3]);
                *(ushort4*)(vtr + ((size_t)(b * H_ + h) * 64 + d) * T_ + t0) = u;
            }
        return;
    }
    Tout* C = (bn < 1024) ? C0 : C1;
    const int nb = bn & 1023;
    #pragma unroll
    for (int mi = 0; mi < MI; ++mi)
        #pragma unroll
        for (int ni = 0; ni < 4; ++ni)
            #pragma unroll
            for (int r = 0; r < 4; ++r) {
                int m = bm + wr * (BM / 2) + mi * 16 + kg * 4 + r;
                int n = nb + wc * 64 + ni * 16 + fr;
                stv(&C[(size_t)m * 1024 + n], acc[mi][ni][r]);
            }
}

// ---------------------------------------------------------------------------
// MFMA sliding-window attention v3. Block = 64 queries of one (b,h).
// K window [klo2,+192) AND V^T window [klo2,+208) staged into LDS via
// global_load_lds with XOR chunk swizzle (chunk c at slot c^(row&7); XOR of
// <=7 flips only low 3 bits so each 8-chunk group is closed -> glld flat-
// contiguous staging stays valid, and all ds_read_b128 are 2-way = free).
// V slots 24,25 (only reachable with koff=48, weight-0 P cols) unswizzled.
// o==q in-place safe (wave-private rows).
// ---------------------------------------------------------------------------
__global__ __launch_bounds__(256) void swa_mfma3(const unsigned short* qb,
                                                 const unsigned short* __restrict__ kb,
                                                 const unsigned short* __restrict__ vt,
                                                 unsigned short* ob) {
    __shared__ unsigned short Ks[192 * 64];        // 24 KB, swizzled
    __shared__ unsigned short Vs[64 * 208];        // 26 KB, swizzled (c<24)
    __shared__ unsigned short Pl[4][16 * 168];     // per-wave P
    const int wave = threadIdx.x >> 6;
    const int lane = threadIdx.x & 63;
    const int blk = blockIdx.x;                    // 0..1023
    const int i0b = (blk & 31) * 64;               // block's first query
    const int bh  = blk >> 5;
    const int h = bh & (H_ - 1), b = bh >> 4;
    const int g = lane >> 4, l15 = lane & 15;

    const size_t rowbase = (size_t)b * T_ * D_ + (size_t)h * DH_;
    const int klo2 = (i0b > 128) ? (i0b - 128) : 0;   // <= 1856

    // ---- stage K rows [klo2, +192), swizzled: lane l -> row l>>3, slot l&7,
    //      fetches global chunk (l&7)^(l>>3) (row&7 == l>>3 for every instr)
    {
        const int lr = lane >> 3;                  // 0..7
        const int gc = (lane & 7) ^ lr;            // global chunk to fetch
        const unsigned short* kg0 = kb + rowbase + (size_t)(klo2 + lr) * D_ + gc * 8;
        #pragma unroll
        for (int s = 0; s < 6; ++s) {
            const int i = wave * 6 + s;            // 24 instrs, 8 rows each
            gload_lds16(kg0 + (size_t)(i * 8) * D_, &Ks[i * 8 * 64]);
        }
    }
    // ---- stage V^T rows d=0..63, cols [klo2, +208), 26 chunks/row ----
    {
        const unsigned short* vtb = vt + (size_t)bh * 64 * T_ + klo2;
        #pragma unroll
        for (int s = 0; s < 7; ++s) {
            const int i = s * 4 + wave;            // wave-uniform
            if (i < 26) {
                const int cc = i * 64 + lane;      // flat chunk 0..1663
                const int d  = cc / 26;
                const int sl = cc - d * 26;        // LDS slot 0..25
                const int c  = (sl < 24) ? (sl ^ (d & 7)) : sl;  // global chunk
                gload_lds16(vtb + (size_t)d * T_ + c * 8, &Vs[i * 512]);
            }
        }
    }

    const int i0  = i0b + wave * 16;
    const int klo = (i0 > 128) ? (i0 - 128) : 0;
    const int koff = klo - klo2;                   // 0,16,32,48

    unsigned short* Pw = Pl[wave];
    {   // zero-pad P cols 144..159 (read by last PV k-tile)
        int row = lane >> 2, col = 144 + (lane & 3) * 4;
        *(uint2*)&Pw[row * 168 + col] = make_uint2(0u, 0u);
    }

    // Q fragments from global (overlaps with staging drain)
    const unsigned short* qrow = qb + rowbase + (size_t)(i0 + l15) * D_ + g * 8;
    const s16x8 aq0 = *(const s16x8*)(qrow);
    const s16x8 aq1 = *(const s16x8*)(qrow + 32);

    __syncthreads();                               // K+V windows visible

    // ---- S = Q K^T over 9 key tiles (B-frags from swizzled Ks) ----
    f32x4 sacc[9];
    #pragma unroll
    for (int t = 0; t < 9; ++t)
        #pragma unroll
        for (int r = 0; r < 4; ++r) sacc[t][r] = 0.f;

    #pragma unroll
    for (int t = 0; t < 9; ++t) {
        const int row = koff + t * 16 + l15;       // <= 191
        const int r7 = row & 7;
        s16x8 b0 = *(const s16x8*)&Ks[row * 64 + ((g     ^ r7) * 8)];
        s16x8 b1 = *(const s16x8*)&Ks[row * 64 + (((g+4) ^ r7) * 8)];
        sacc[t] = __builtin_amdgcn_mfma_f32_16x16x32_bf16(aq0, b0, sacc[t], 0, 0, 0);
        sacc[t] = __builtin_amdgcn_mfma_f32_16x16x32_bf16(aq1, b1, sacc[t], 0, 0, 0);
    }

    // ---- mask + scale + softmax (C/D layout: row g*4+r, col l15) ----
    float mrow[4] = {-1e30f, -1e30f, -1e30f, -1e30f};
    #pragma unroll
    for (int t = 0; t < 9; ++t)
        #pragma unroll
        for (int r = 0; r < 4; ++r) {
            const int j  = klo + t * 16 + l15;
            const int iq = i0 + g * 4 + r;
            const bool valid = (j <= iq) && (j + 128 >= iq);
            const float s = valid ? sacc[t][r] * 0.125f : -1e30f;
            sacc[t][r] = s;
            mrow[r] = fmaxf(mrow[r], s);
        }
    #pragma unroll
    for (int r = 0; r < 4; ++r)
        #pragma unroll
        for (int off = 1; off < 16; off <<= 1)
            mrow[r] = fmaxf(mrow[r], __shfl_xor(mrow[r], off));

    float lrow[4] = {0.f, 0.f, 0.f, 0.f};
    #pragma unroll
    for (int t = 0; t < 9; ++t)
        #pragma unroll
        for (int r = 0; r < 4; ++r) {
            const float p = __expf(sacc[t][r] - mrow[r]);
            sacc[t][r] = p;
            lrow[r] += p;
        }
    #pragma unroll
    for (int r = 0; r < 4; ++r) {
        #pragma unroll
        for (int off = 1; off < 16; off <<= 1)
            lrow[r] += __shfl_xor(lrow[r], off);
    }
    float invl[4];
    #pragma unroll
    for (int r = 0; r < 4; ++r) invl[r] = 1.f / lrow[r];

    // ---- P (bf16) -> per-wave LDS (same-wave write->read, no barrier) ----
    #pragma unroll
    for (int t = 0; t < 9; ++t)
        #pragma unroll
        for (int r = 0; r < 4; ++r)
            Pw[(g * 4 + r) * 168 + t * 16 + l15] = f2bf(sacc[t][r]);

    // ---- O = P V : A = P from LDS, B = V^T rows from swizzled Vs ----
    f32x4 oacc[4];
    #pragma unroll
    for (int nt = 0; nt < 4; ++nt)
        #pragma unroll
        for (int r = 0; r < 4; ++r) oacc[nt][r] = 0.f;

    const int kc0 = koff >> 3;                     // 0,2,4,6
    #pragma unroll
    for (int kt = 0; kt < 5; ++kt) {
        const s16x8 ap = *(const s16x8*)&Pw[l15 * 168 + kt * 32 + g * 8];
        #pragma unroll
        for (int nt = 0; nt < 4; ++nt) {
            const int d = nt * 16 + l15;
            const int c = kc0 + kt * 4 + g;        // global chunk 0..25
            const int sl = (c < 24) ? (c ^ (d & 7)) : c;
            s16x8 bv = *(const s16x8*)&Vs[d * 208 + sl * 8];
            oacc[nt] = __builtin_amdgcn_mfma_f32_16x16x32_bf16(ap, bv, oacc[nt], 0, 0, 0);
        }
    }

    #pragma unroll
    for (int nt = 0; nt < 4; ++nt)
        #pragma unroll
        for (int r = 0; r < 4; ++r) {
            const float val = oacc[nt][r] * invl[r];
            ob[rowbase + (size_t)(i0 + g * 4 + r) * D_ + nt * 16 + l15] = f2bf(val);
        }
}

extern "C" void kernel_launch(void* const* d_in, const int* in_sizes, int n_in,
                              void* d_out, int out_size, void* d_ws, size_t ws_size,
                              hipStream_t stream) {
    const float* x  = (const float*)d_in[0];
    const float* Wq = (const float*)d_in[1];
    const float* Wk = (const float*)d_in[2];
    const float* Wv = (const float*)d_in[3];
    const float* Wo = (const float*)d_in[4];

    const size_t MD = (size_t)M_ * D_;      // 4,194,304
    const size_t WN = (size_t)D_ * D_;      // 1,048,576

    // ws (bf16): xb | Wqb|Wkb|Wvb | Wob | qb  = 24 MB
    unsigned short* wsb = (unsigned short*)d_ws;
    unsigned short* xb  = wsb;
    unsigned short* Wqb = xb + MD;          // Wq|Wk|Wv adjacent = merged B matrix
    unsigned short* Wob = Wqb + 3 * WN;
    unsigned short* qb  = Wob + WN;
    // d_out doubles as vt | kb until the final GEMM overwrites it.
    // vt FIRST: swa's V-window tail over-reads land in kb, never past d_out.
    unsigned short* vt = (unsigned short*)d_out;
    unsigned short* kb = vt + MD;

    conv_bf16<<<8192, 256, 0, stream>>>(x, Wq, Wk, Wv, Wo, wsb);

    // merged QKV projection: N = 3072, 768 blocks (3/CU); V written transposed
    gemm_m97<128, 2, unsigned short><<<dim3(24, M_ / 128), 256, 0, stream>>>(
        xb, Wqb, qb, kb, vt, D_);

    swa_mfma3<<<(B_ * H_ * T_) / 64, 256, 0, stream>>>(qb, kb, vt, qb);

    // output projection: N = 1024, BM=64, BK=128 (32 MFMAs/barrier, 8 iters)
    gemm_m97<64, 4, float><<<dim3(8, M_ / 64), 256, 0, stream>>>(
        qb, Wob, (float*)d_out, (float*)d_out, nullptr, D_);
}